// Round 7
// baseline (9116.541 us; speedup 1.0000x reference)
//
#include <hip/hip_runtime.h>
#include <hip/hip_fp16.h>
#include <cstdint>

typedef float f4 __attribute__((ext_vector_type(4)));
typedef unsigned long long u64;

// Problem constants
// B=32, F=34, T=1000, K=7, S=3, F_DOWN=10, C=64, H=640, 3H=1920, T_MAX=9, PAD=4, MS_KS=200

// ---------------------------------------------------------------------------
// K1: build DCLS kernel dk[h][i][tau], h<640, i<14, tau<9
__global__ void k_dk(const float* __restrict__ dcls_w, const float* __restrict__ dcls_p,
                     float* __restrict__ dk) {
    int idx = blockIdx.x * 256 + threadIdx.x;
    if (idx >= 640 * 126) return;
    int h = idx / 126;
    int r = idx % 126;
    int i = r / 9;
    int tau = r % 9;
    float p = dcls_p[h * 14 + i];
    p = fminf(fmaxf(p, 0.f), 8.f);
    float tri = fmaxf(1.f - fabsf((float)tau - p), 0.f);
    dk[idx] = dcls_w[h * 14 + i] * tri;
}

// ---------------------------------------------------------------------------
// K2: EMA lowpass (200-tap truncated, exact) + highpass. hp[b][f][t]
__global__ void k_ema(const float* __restrict__ x, const float* __restrict__ a_vals,
                      const float* __restrict__ w_vals, float* __restrict__ hp) {
    __shared__ float xr[1024];
    int bf = blockIdx.x;               // b*34+f
    int f = bf % 34;
    int tid = threadIdx.x;
    const float* xs = x + (size_t)bf * 1000;
    for (int i = tid; i < 1000; i += 256) xr[i] = xs[i];
    for (int i = 1000 + tid; i < 1024; i += 256) xr[i] = 0.f;
    __syncthreads();
    float a = a_vals[f], wv = w_vals[f];
    float om = 1.f - a;
    int t1 = tid, t2 = tid + 256, t3 = tid + 512, t4 = tid + 768;
    bool v4 = (t4 < 1000);
    float a0 = 0.f, a1 = 0.f, a2 = 0.f, a3 = 0.f;
    float coef = a;
    for (int k = 0; k < 200; ++k) {
        a0 += (k <= t1 ? xr[t1 - k] : 0.f) * coef;
        a1 += xr[t2 - k] * coef;
        a2 += xr[t3 - k] * coef;
        a3 += (v4 ? xr[t4 - k] : 0.f) * coef;
        coef *= om;
    }
    float* op = hp + (size_t)bf * 1000;
    op[t1] = xr[t1] - wv * a0;
    op[t2] = xr[t2] - wv * a1;
    op[t3] = xr[t3] - wv * a2;
    if (v4) op[t4] = xr[t4] - wv * a3;
}

// ---------------------------------------------------------------------------
// K3: DCLS grouped conv. ybcgt[b][h=c*10+g][t] = bias[g*64+c] + sum_{i,tau} u * dk
__global__ void __launch_bounds__(256) k_conv(const float* __restrict__ hp,
                                              const float* __restrict__ dk,
                                              const float* __restrict__ dcls_b,
                                              float* __restrict__ ybcgt) {
    __shared__ float u[2 * 7 * 264];    // [pm][kk][264]
    __shared__ float dks[64 * 126];
    int tid = threadIdx.x;
    int t0 = blockIdx.x * 256;
    int g = blockIdx.y;
    int b = blockIdx.z;
    for (int idx = tid; idx < 8064; idx += 256) dks[idx] = dk[g * 8064 + idx];
    for (int idx = tid; idx < 3696; idx += 256) {
        int pm = idx / 1848;
        int rem = idx % 1848;
        int kk = rem / 264;
        int tt = rem % 264;
        int tg = t0 - 4 + tt;
        float v = (tg >= 0 && tg < 1000) ? hp[((size_t)(b * 34 + g * 3 + kk)) * 1000 + tg] : 0.f;
        u[idx] = pm ? fmaxf(-v, 0.f) : fmaxf(v, 0.f);
    }
    __syncthreads();
    int tl = tid & 63;
    int cg4 = tid >> 6;     // 0..3, c = cg4*16+ci
    float acc[16][4];
#pragma unroll
    for (int ci = 0; ci < 16; ++ci)
#pragma unroll
        for (int tq = 0; tq < 4; ++tq) acc[ci][tq] = 0.f;

    for (int i = 0; i < 14; ++i) {
#pragma unroll
        for (int tau = 0; tau < 9; ++tau) {
            const float* ub = u + i * 264 + tl + tau;
            float u0 = ub[0];
            float u1 = ub[64];
            float u2 = ub[128];
            float u3 = ub[192];
            const float* dp = dks + cg4 * 16 * 126 + i * 9 + tau;
#pragma unroll
            for (int ci = 0; ci < 16; ++ci) {
                float dv = dp[ci * 126];
                acc[ci][0] += u0 * dv;
                acc[ci][1] += u1 * dv;
                acc[ci][2] += u2 * dv;
                acc[ci][3] += u3 * dv;
            }
        }
    }
#pragma unroll
    for (int ci = 0; ci < 16; ++ci) {
        int c = cg4 * 16 + ci;
        float bias = dcls_b[g * 64 + c];
        size_t base = ((size_t)(b * 640 + c * 10 + g)) * 1000;
#pragma unroll
        for (int tq = 0; tq < 4; ++tq) {
            int t = t0 + tq * 64 + tl;
            if (t < 1000) ybcgt[base + t] = acc[ci][tq] + bias;
        }
    }
}

// ---------------------------------------------------------------------------
// K4: BN stats: per channel c sum & sumsq over (b,g,t). bnsum[0..63]=sum, [64..127]=sumsq
__global__ void k_bnstat(const float* __restrict__ ybcgt, float* __restrict__ bnsum) {
    int c = blockIdx.x / 10;
    int g = blockIdx.x % 10;
    int tid = threadIdx.x;
    float s = 0.f, q = 0.f;
    const float* base = ybcgt + ((size_t)(c * 10 + g)) * 1000;
    for (int b = 0; b < 32; ++b) {
        const float* p = base + (size_t)b * 640000;
        for (int t = tid; t < 1000; t += 256) {
            float v = p[t];
            s += v;
            q += v * v;
        }
    }
    for (int off = 1; off < 64; off <<= 1) {
        s += __shfl_xor(s, off);
        q += __shfl_xor(q, off);
    }
    __shared__ float rs[4], rq[4];
    if ((tid & 63) == 0) { rs[tid >> 6] = s; rq[tid >> 6] = q; }
    __syncthreads();
    if (tid == 0) {
        s = rs[0] + rs[1] + rs[2] + rs[3];
        q = rq[0] + rq[1] + rq[2] + rq[3];
        atomicAdd(&bnsum[c], s);
        atomicAdd(&bnsum[64 + c], q);
    }
}

// K5: BN finalize -> bnp[c]=scale, bnp[64+c]=shift
__global__ void k_bnfin(const float* __restrict__ bnsum, const float* __restrict__ gamma,
                        const float* __restrict__ beta, float* __restrict__ bnp) {
    int c = threadIdx.x;
    const float inv_n = 1.f / 320000.f;
    float mean = bnsum[c] * inv_n;
    float var = bnsum[64 + c] * inv_n - mean * mean;
    float sc = gamma[c] * rsqrtf(var + 1e-5f);
    bnp[c] = sc;
    bnp[64 + c] = beta[c] - mean * sc;
}

// ---------------------------------------------------------------------------
// K6: fused transpose + BN + sigmoid: seq[(t*32+b)*640 + h] = sigmoid(scale*y + shift) (fp16)
__global__ void k_tr(const float* __restrict__ ybcgt, const float* __restrict__ bnp,
                     __half* __restrict__ seq) {
    __shared__ float tile[64 * 65];
    int tid = threadIdx.x;
    int tt0 = blockIdx.x * 64;
    int h0 = blockIdx.y * 64;
    int b = blockIdx.z;
    int tx = tid & 63;
    int ty = tid >> 6;
#pragma unroll
    for (int r = 0; r < 16; ++r) {
        int hh = r * 4 + ty;
        int t = tt0 + tx;
        float v = (t < 1000) ? ybcgt[((size_t)(b * 640 + h0 + hh)) * 1000 + t] : 0.f;
        int c = (h0 + hh) / 10;
        float sarg = bnp[c] * v + bnp[64 + c];
        tile[hh * 65 + tx] = 1.f / (1.f + __expf(-sarg));
    }
    __syncthreads();
#pragma unroll
    for (int r = 0; r < 16; ++r) {
        int t = tt0 + r * 4 + ty;
        if (t < 1000)
            seq[((size_t)t * 32 + b) * 640 + h0 + tx] = __float2half(tile[tx * 65 + r * 4 + ty]);
    }
}

// ---------------------------------------------------------------------------
// K7: x_proj GEMM: xp[m][n] = sum_k seq[m][k]*W_ih[n][k] + b_ih[n]
// M=32000, N=1920, K=640. BM=BN=128, BK=8, 256 thr, 8x8 micro via 16 NAMED f4 accs.
// __launch_bounds__(256,4): VGPR cap 128 (default cap of 64 was spilling: VGPR_Count=52).
// Bs columns swizzled (c + (c>>5)*4) to break the tx-stride-8 4-way bank alias.
#define BCOL(c) ((c) + (((c) >> 5) << 2))
__global__ void __launch_bounds__(256, 4) k_gemm(const __half* __restrict__ A,
                                                 const float* __restrict__ W,
                                                 const float* __restrict__ bih,
                                                 __half* __restrict__ C) {
    __shared__ float As[8][128];
    __shared__ float Bs[8][140];
    int tid = threadIdx.x;
    int n0 = blockIdx.x * 128;
    int m0 = blockIdx.y * 128;
    int tx = tid & 15;          // n-subtile: cols n0 + tx*8 .. +7
    int ty = tid >> 4;          // m-subtile: rows m0 + ty*8 .. +7
    int lm = tid >> 1;
    int lk4 = (tid & 1) * 4;
    int lmB = BCOL(lm);
    const int bc0 = BCOL(tx * 8);
    const int bc1 = BCOL(tx * 8 + 4);
    const __half* Ab = A + (size_t)(m0 + lm) * 640 + lk4;
    const float* Bb = W + (size_t)(n0 + lm) * 640 + lk4;

    f4 c0a = {0,0,0,0}, c0b = {0,0,0,0}, c1a = {0,0,0,0}, c1b = {0,0,0,0};
    f4 c2a = {0,0,0,0}, c2b = {0,0,0,0}, c3a = {0,0,0,0}, c3b = {0,0,0,0};
    f4 c4a = {0,0,0,0}, c4b = {0,0,0,0}, c5a = {0,0,0,0}, c5b = {0,0,0,0};
    f4 c6a = {0,0,0,0}, c6b = {0,0,0,0}, c7a = {0,0,0,0}, c7b = {0,0,0,0};

    for (int kt = 0; kt < 80; ++kt) {
        float2 araw = *(const float2*)(Ab + (size_t)kt * 8);   // 4 halves
        const __half2* ah = (const __half2*)&araw;
        float2 a01 = __half22float2(ah[0]);
        float2 a23 = __half22float2(ah[1]);
        float4 bv = *(const float4*)(Bb + (size_t)kt * 8);
        __syncthreads();
        As[lk4 + 0][lm] = a01.x; As[lk4 + 1][lm] = a01.y;
        As[lk4 + 2][lm] = a23.x; As[lk4 + 3][lm] = a23.y;
        Bs[lk4 + 0][lmB] = bv.x; Bs[lk4 + 1][lmB] = bv.y;
        Bs[lk4 + 2][lmB] = bv.z; Bs[lk4 + 3][lmB] = bv.w;
        __syncthreads();
#pragma unroll
        for (int kk = 0; kk < 8; ++kk) {
            f4 blo = *(const f4*)&Bs[kk][bc0];
            f4 bhi = *(const f4*)&Bs[kk][bc1];
            f4 alo = *(const f4*)&As[kk][ty * 8];
            f4 ahi = *(const f4*)&As[kk][ty * 8 + 4];
            c0a += alo.x * blo; c0b += alo.x * bhi;
            c1a += alo.y * blo; c1b += alo.y * bhi;
            c2a += alo.z * blo; c2b += alo.z * bhi;
            c3a += alo.w * blo; c3b += alo.w * bhi;
            c4a += ahi.x * blo; c4b += ahi.x * bhi;
            c5a += ahi.y * blo; c5b += ahi.y * bhi;
            c6a += ahi.z * blo; c6b += ahi.z * bhi;
            c7a += ahi.w * blo; c7b += ahi.w * bhi;
        }
    }
    f4 bblo = *(const f4*)&bih[n0 + tx * 8];
    f4 bbhi = *(const f4*)&bih[n0 + tx * 8 + 4];
    union { __half h[8]; float4 v; } ob;
#define STORE_ROW(i, ra, rb)                                                     \
    {                                                                            \
        f4 lo = ra + bblo; f4 hi = rb + bbhi;                                    \
        ob.h[0] = __float2half(lo.x); ob.h[1] = __float2half(lo.y);              \
        ob.h[2] = __float2half(lo.z); ob.h[3] = __float2half(lo.w);              \
        ob.h[4] = __float2half(hi.x); ob.h[5] = __float2half(hi.y);              \
        ob.h[6] = __float2half(hi.z); ob.h[7] = __float2half(hi.w);              \
        *(float4*)&C[(size_t)(m0 + ty * 8 + i) * 1920 + n0 + tx * 8] = ob.v;     \
    }
    STORE_ROW(0, c0a, c0b) STORE_ROW(1, c1a, c1b) STORE_ROW(2, c2a, c2b)
    STORE_ROW(3, c3a, c3b) STORE_ROW(4, c4a, c4b) STORE_ROW(5, c5a, c5b)
    STORE_ROW(6, c6a, c6b) STORE_ROW(7, c7a, c7b)
#undef STORE_ROW
}

// ---------------------------------------------------------------------------
// K8: persistent GRU (cooperative launch for co-residency).
// h exchange: fp16 packed 4/u64, L3-direct AGENT relaxed atomics.
// Staging is 2-chunk pipelined: 20 loads issued, unpack/compute chunk A (k<320)
// while chunk B lands. Barrier: 8 x 128B fetch_add lines + tid0 sum-detect
// (round-5 scheme: lowest measured poll contention).
__global__ void __launch_bounds__(256, 1) k_gru(const __half* __restrict__ xp,
                                                const float* __restrict__ Whh,
                                                const float* __restrict__ bhh,
                                                const float* __restrict__ fcw,
                                                u64* __restrict__ hgu,
                                                float* __restrict__ fcpart,
                                                unsigned* __restrict__ bar) {
    __shared__ __align__(16) float w_lds[640 * 16];   // [k][jj*4+g], g<3  (40960 B)
    __shared__ __align__(16) float h_lds[640 * 33];   // h staging, stride 33 (84480 B)
    float* red = h_lds;            // overlay after compute: [w][16][24] = 1536 floats
    float* fcred = h_lds + 1536;   // 128 floats

    const int tid = threadIdx.x;
    const int blk = blockIdx.x;
    const int j0 = blk * 4;
    const int ksx = tid >> 4;
    const int jj = (tid >> 2) & 3;
    const int bg = tid & 3;
    const int lane = tid & 63;
    const int wid = tid >> 6;

    // Load the block's 12 W_hh rows into LDS once (persists across all steps)
    for (int r = 0; r < 12; ++r) {
        int wjj = r / 3, wg = r % 3;
        const float* src = Whh + (size_t)(wg * 640 + j0 + wjj) * 640;
        for (int k = tid; k < 640; k += 256) w_lds[k * 16 + wjj * 4 + wg] = src[k];
    }
    float bh_r = 0.f, bh_z = 0.f, bh_n = 0.f, fw = 0.f, hold = 0.f;
    if (tid < 128) {
        int fj = j0 + (tid >> 5);
        bh_r = bhh[fj];
        bh_z = bhh[640 + fj];
        bh_n = bhh[1280 + fj];
        fw = fcw[fj];
    }
    __syncthreads();

    // preload xp for t=0 (plain cached loads)
    float xr = 0.f, xz = 0.f, xn = 0.f;
    if (tid < 128) {
        const __half* xpt = xp + (size_t)(tid & 31) * 1920;
        int j = j0 + (tid >> 5);
        xr = __half2float(xpt[j]);
        xz = __half2float(xpt[640 + j]);
        xn = __half2float(xpt[1280 + j]);
    }

    for (int t = 0; t < 1000; ++t) {
        const u64* hcur = hgu + (size_t)(t & 1) * 5120;
        u64* hnxt = hgu + (size_t)((t + 1) & 1) * 5120;

        // issue all 20 staging loads (2 chunks of 10)
        u64 rrA[10], rrB[10];
#pragma unroll
        for (int i = 0; i < 10; ++i)
            rrA[i] = __hip_atomic_load(&hcur[i * 256 + tid],
                                       __ATOMIC_RELAXED, __HIP_MEMORY_SCOPE_AGENT);
#pragma unroll
        for (int i = 0; i < 10; ++i)
            rrB[i] = __hip_atomic_load(&hcur[2560 + i * 256 + tid],
                                       __ATOMIC_RELAXED, __HIP_MEMORY_SCOPE_AGENT);
        // unpack chunk A (k < 320); compiler waits only the first 10 loads
#pragma unroll
        for (int i = 0; i < 10; ++i) {
            int e = i * 256 + tid;             // e = k*8 + b/4
            union { u64 u; __half2 h2[2]; } pk;
            pk.u = rrA[i];
            float2 lo = __half22float2(pk.h2[0]);
            float2 hi = __half22float2(pk.h2[1]);
            f4 v = {lo.x, lo.y, hi.x, hi.y};
            *(f4*)&h_lds[(e >> 3) * 33 + (e & 7) * 4] = v;
        }
        __syncthreads();

        // prefetch xp for step t+1 (overlaps with compute below)
        float nxr = 0.f, nxz = 0.f, nxn = 0.f;
        if (t + 1 < 1000 && tid < 128) {
            const __half* xpt = xp + (size_t)(t + 1) * 61440 + (size_t)(tid & 31) * 1920;
            int j = j0 + (tid >> 5);
            nxr = __half2float(xpt[j]);
            nxz = __half2float(xpt[640 + j]);
            nxn = __half2float(xpt[1280 + j]);
        }

        float a0[8], a1[8], a2[8];
#pragma unroll
        for (int i = 0; i < 8; ++i) { a0[i] = 0.f; a1[i] = 0.f; a2[i] = 0.f; }

        // compute chunk A (k < 320) while chunk B loads land
#pragma unroll 4
        for (int ii = 0; ii < 20; ++ii) {
            int k = ii * 16 + ksx;
            float4 wv = *(const float4*)(w_lds + k * 16 + jj * 4);
            float4 h0 = *(const float4*)(h_lds + k * 33 + bg * 8);
            float4 h1 = *(const float4*)(h_lds + k * 33 + bg * 8 + 4);
            a0[0] += wv.x * h0.x; a0[1] += wv.x * h0.y; a0[2] += wv.x * h0.z; a0[3] += wv.x * h0.w;
            a0[4] += wv.x * h1.x; a0[5] += wv.x * h1.y; a0[6] += wv.x * h1.z; a0[7] += wv.x * h1.w;
            a1[0] += wv.y * h0.x; a1[1] += wv.y * h0.y; a1[2] += wv.y * h0.z; a1[3] += wv.y * h0.w;
            a1[4] += wv.y * h1.x; a1[5] += wv.y * h1.y; a1[6] += wv.y * h1.z; a1[7] += wv.y * h1.w;
            a2[0] += wv.z * h0.x; a2[1] += wv.z * h0.y; a2[2] += wv.z * h0.z; a2[3] += wv.z * h0.w;
            a2[4] += wv.z * h1.x; a2[5] += wv.z * h1.y; a2[6] += wv.z * h1.z; a2[7] += wv.z * h1.w;
        }
        // unpack chunk B (k in [320,640)) and sync before reading it
#pragma unroll
        for (int i = 0; i < 10; ++i) {
            int e = 2560 + i * 256 + tid;
            union { u64 u; __half2 h2[2]; } pk;
            pk.u = rrB[i];
            float2 lo = __half22float2(pk.h2[0]);
            float2 hi = __half22float2(pk.h2[1]);
            f4 v = {lo.x, lo.y, hi.x, hi.y};
            *(f4*)&h_lds[(e >> 3) * 33 + (e & 7) * 4] = v;
        }
        __syncthreads();
#pragma unroll 4
        for (int ii = 20; ii < 40; ++ii) {
            int k = ii * 16 + ksx;
            float4 wv = *(const float4*)(w_lds + k * 16 + jj * 4);
            float4 h0 = *(const float4*)(h_lds + k * 33 + bg * 8);
            float4 h1 = *(const float4*)(h_lds + k * 33 + bg * 8 + 4);
            a0[0] += wv.x * h0.x; a0[1] += wv.x * h0.y; a0[2] += wv.x * h0.z; a0[3] += wv.x * h0.w;
            a0[4] += wv.x * h1.x; a0[5] += wv.x * h1.y; a0[6] += wv.x * h1.z; a0[7] += wv.x * h1.w;
            a1[0] += wv.y * h0.x; a1[1] += wv.y * h0.y; a1[2] += wv.y * h0.z; a1[3] += wv.y * h0.w;
            a1[4] += wv.y * h1.x; a1[5] += wv.y * h1.y; a1[6] += wv.y * h1.z; a1[7] += wv.y * h1.w;
            a2[0] += wv.z * h0.x; a2[1] += wv.z * h0.y; a2[2] += wv.z * h0.z; a2[3] += wv.z * h0.w;
            a2[4] += wv.z * h1.x; a2[5] += wv.z * h1.y; a2[6] += wv.z * h1.z; a2[7] += wv.z * h1.w;
        }
        // reduce over 4 ksx within each wave (lane distance 16, 32)
#pragma unroll
        for (int i = 0; i < 8; ++i) {
            a0[i] += __shfl_xor(a0[i], 16); a0[i] += __shfl_xor(a0[i], 32);
            a1[i] += __shfl_xor(a1[i], 16); a1[i] += __shfl_xor(a1[i], 32);
            a2[i] += __shfl_xor(a2[i], 16); a2[i] += __shfl_xor(a2[i], 32);
        }
        __syncthreads();   // h_lds reads done; safe to reuse as 'red'
        if (lane < 16) {
            float* rp = red + (wid * 16 + lane) * 24;
#pragma unroll
            for (int i = 0; i < 8; ++i) { rp[i] = a0[i]; rp[8 + i] = a1[i]; rp[16 + i] = a2[i]; }
        }
        __syncthreads();
        if (tid < 128) {
            int fb = tid & 31;
            int rr_ = ((tid >> 5) << 2) | (fb >> 3);
            int bif = fb & 7;
            float hr = bh_r, hz = bh_z, hn = bh_n;
#pragma unroll
            for (int w2 = 0; w2 < 4; ++w2) {
                const float* rp = red + (w2 * 16 + rr_) * 24;
                hr += rp[bif];
                hz += rp[8 + bif];
                hn += rp[16 + bif];
            }
            int j = j0 + (tid >> 5);
            float r_ = 1.f / (1.f + __expf(-(xr + hr)));
            float z_ = 1.f / (1.f + __expf(-(xz + hz)));
            float pre = xn + r_ * hn;
            float e2 = __expf(-2.f * fabsf(pre));
            float tn = (1.f - e2) / (1.f + e2);
            float n_ = (pre >= 0.f) ? tn : -tn;
            float hnew = (1.f - z_) * n_ + z_ * hold;
            hold = hnew;
            // pack 4 consecutive b into one u64 of halves; store FIRST (drain overlap)
            float h1v = __shfl_xor(hnew, 1);
            float lo_f = (fb & 1) ? h1v : hnew;
            float hi_f = (fb & 1) ? hnew : h1v;
            __half2 v2 = __floats2half2_rn(lo_f, hi_f);
            union { __half2 h2; unsigned u; } cv;
            cv.h2 = v2;
            unsigned pa = cv.u;
            unsigned pb = (unsigned)__shfl_xor((int)pa, 2);
            u64 pku = ((fb & 2) == 0) ? ((u64)pa | ((u64)pb << 32))
                                      : ((u64)pb | ((u64)pa << 32));
            if ((fb & 3) == 0)
                __hip_atomic_store(&hnxt[j * 8 + (fb >> 2)], pku,
                                   __ATOMIC_RELAXED, __HIP_MEMORY_SCOPE_AGENT);
            fcred[tid] = hnew * fw;
            // drain this wave's h stores to L3 before arrival below
            __builtin_amdgcn_s_waitcnt(0);
        }
        xr = nxr; xz = nxz; xn = nxn;
        __syncthreads();
        if (tid < 32) {
            if (tid == 0)   // arrival first: fire-and-forget RMW, overlaps fc work
                __hip_atomic_fetch_add(&bar[(blk & 7) * 32], 1u,
                                       __ATOMIC_RELAXED, __HIP_MEMORY_SCOPE_AGENT);
            float s = fcred[tid] + fcred[32 + tid] + fcred[64 + tid] + fcred[96 + tid];
            __hip_atomic_store(&fcpart[(size_t)blk * 32000 + t * 32 + tid], s,
                               __ATOMIC_RELAXED, __HIP_MEMORY_SCOPE_AGENT);
        }
        // ---- monotone 8-line grid barrier: tid0 sums 8 counters ----
        if (tid == 0) {
            unsigned target = 160u * (unsigned)(t + 1);
            for (;;) {
                unsigned s = 0;
#pragma unroll
                for (int i = 0; i < 8; ++i)
                    s += __hip_atomic_load(&bar[i * 32], __ATOMIC_RELAXED,
                                           __HIP_MEMORY_SCOPE_AGENT);
                if (s >= target) break;
                __builtin_amdgcn_s_sleep(1);
            }
        }
        __syncthreads();
        __atomic_signal_fence(__ATOMIC_SEQ_CST);   // compiler-only ordering
    }
}

// ---------------------------------------------------------------------------
// K9: final fc reduction: out[b*1000+t] = fc_b + sum_blk fcpart[blk][t][b]
__global__ void k_fc(const float* __restrict__ fcpart, const float* __restrict__ fcb,
                     float* __restrict__ out) {
    int gid = blockIdx.x * 256 + threadIdx.x;  // < 32000
    int t = gid >> 5;
    int b = gid & 31;
    float s = fcb[0];
    for (int blk = 0; blk < 160; ++blk) s += fcpart[(size_t)blk * 32000 + t * 32 + b];
    out[(size_t)b * 1000 + t] = s;
}

// ---------------------------------------------------------------------------
extern "C" void kernel_launch(void* const* d_in, const int* in_sizes, int n_in,
                              void* d_out, int out_size, void* d_ws, size_t ws_size,
                              hipStream_t stream) {
    const float* x      = (const float*)d_in[0];
    const float* a_vals = (const float*)d_in[1];
    const float* w_vals = (const float*)d_in[2];
    const float* dcls_w = (const float*)d_in[3];
    const float* dcls_p = (const float*)d_in[4];
    const float* dcls_b = (const float*)d_in[5];
    const float* gamma  = (const float*)d_in[6];
    const float* beta   = (const float*)d_in[7];
    const float* W_ih   = (const float*)d_in[8];
    const float* W_hh   = (const float*)d_in[9];
    const float* b_ih   = (const float*)d_in[10];
    const float* b_hh   = (const float*)d_in[11];
    const float* fc_w   = (const float*)d_in[12];
    const float* fc_b   = (const float*)d_in[13];
    char* w = (char*)d_ws;

    // ws layout (bytes). Peak total: ~164.0 MB.
    //   [0, 122,880,000)           xpH   fp16 32000x1920  -- phase D
    //       overlay [0, 81,920,000)        ybcgt fp32     -- phases A-B (dead before GEMM)
    //   [122,880,000, 163,840,000) seqH  fp16 32000x640   -- phases B-C
    //       overlay: hp fp32 + dk fp32  -- phase A;  fcpart fp32 -- phase D
    //   [163,840,000, 163,921,920) hgu   u64 2x5120 (h dbuf, 4 packed fp16 per u64)
    //   [163,921,920, 163,942,400) bar   u32 160x32 (128B lines; only 8 used)
    //   [164,003,840, 164,004,352) bnsum fp32 128
    //   [164,004,352, 164,004,864) bnp   fp32 128
    __half* xpH    = (__half*)(w);
    float* ybcgt   = (float*)(w);
    __half* seqH   = (__half*)(w + 122880000);
    float* hp      = (float*)(w + 122880000);
    float* dk      = (float*)(w + 122880000 + 4352000);
    float* fcpart  = (float*)(w + 122880000);
    u64* hgu       = (u64*)(w + 163840000);
    unsigned* bar  = (unsigned*)(w + 163921920);
    float* bnsum   = (float*)(w + 164003840);

    // zero h0 double-buffer + barrier counters + bn accumulators + bnp (contiguous tail)
    hipMemsetAsync(w + 163840000, 0, 164864, stream);

    k_dk<<<dim3(315), dim3(256), 0, stream>>>(dcls_w, dcls_p, dk);
    k_ema<<<dim3(1088), dim3(256), 0, stream>>>(x, a_vals, w_vals, hp);
    k_conv<<<dim3(4, 10, 32), dim3(256), 0, stream>>>(hp, dk, dcls_b, ybcgt);
    k_bnstat<<<dim3(640), dim3(256), 0, stream>>>(ybcgt, bnsum);
    k_bnfin<<<dim3(1), dim3(64), 0, stream>>>(bnsum, gamma, beta, (float*)(w + 164004352));
    k_tr<<<dim3(16, 10, 32), dim3(256), 0, stream>>>(ybcgt, (float*)(w + 164004352), seqH);
    k_gemm<<<dim3(15, 250), dim3(256), 0, stream>>>(seqH, W_ih, b_ih, xpH);

    {
        const __half* xp_a = xpH;
        void* args[] = {(void*)&xp_a, (void*)&W_hh, (void*)&b_hh, (void*)&fc_w,
                        (void*)&hgu, (void*)&fcpart, (void*)&bar};
        hipLaunchCooperativeKernel((void*)k_gru, dim3(160), dim3(256), args, 0, stream);
    }

    k_fc<<<dim3(125), dim3(256), 0, stream>>>(fcpart, fc_b, (float*)d_out);
}

// Round 10
// 7440.982 us; speedup vs baseline: 1.2252x; 1.2252x over previous
//
#include <hip/hip_runtime.h>
#include <hip/hip_fp16.h>
#include <cstdint>

typedef float f4 __attribute__((ext_vector_type(4)));
typedef unsigned long long u64;

// Problem constants
// B=32, F=34, T=1000, K=7, S=3, F_DOWN=10, C=64, H=640, 3H=1920, T_MAX=9, PAD=4, MS_KS=200

// ---------------------------------------------------------------------------
// K1: build DCLS kernel dk[h][i][tau], h<640, i<14, tau<9
__global__ void k_dk(const float* __restrict__ dcls_w, const float* __restrict__ dcls_p,
                     float* __restrict__ dk) {
    int idx = blockIdx.x * 256 + threadIdx.x;
    if (idx >= 640 * 126) return;
    int h = idx / 126;
    int r = idx % 126;
    int i = r / 9;
    int tau = r % 9;
    float p = dcls_p[h * 14 + i];
    p = fminf(fmaxf(p, 0.f), 8.f);
    float tri = fmaxf(1.f - fabsf((float)tau - p), 0.f);
    dk[idx] = dcls_w[h * 14 + i] * tri;
}

// ---------------------------------------------------------------------------
// K2: EMA lowpass (200-tap truncated, exact) + highpass. hp[b][f][t]
__global__ void k_ema(const float* __restrict__ x, const float* __restrict__ a_vals,
                      const float* __restrict__ w_vals, float* __restrict__ hp) {
    __shared__ float xr[1024];
    int bf = blockIdx.x;               // b*34+f
    int f = bf % 34;
    int tid = threadIdx.x;
    const float* xs = x + (size_t)bf * 1000;
    for (int i = tid; i < 1000; i += 256) xr[i] = xs[i];
    for (int i = 1000 + tid; i < 1024; i += 256) xr[i] = 0.f;
    __syncthreads();
    float a = a_vals[f], wv = w_vals[f];
    float om = 1.f - a;
    int t1 = tid, t2 = tid + 256, t3 = tid + 512, t4 = tid + 768;
    bool v4 = (t4 < 1000);
    float a0 = 0.f, a1 = 0.f, a2 = 0.f, a3 = 0.f;
    float coef = a;
    for (int k = 0; k < 200; ++k) {
        a0 += (k <= t1 ? xr[t1 - k] : 0.f) * coef;
        a1 += xr[t2 - k] * coef;
        a2 += xr[t3 - k] * coef;
        a3 += (v4 ? xr[t4 - k] : 0.f) * coef;
        coef *= om;
    }
    float* op = hp + (size_t)bf * 1000;
    op[t1] = xr[t1] - wv * a0;
    op[t2] = xr[t2] - wv * a1;
    op[t3] = xr[t3] - wv * a2;
    if (v4) op[t4] = xr[t4] - wv * a3;
}

// ---------------------------------------------------------------------------
// K3: DCLS grouped conv. ybcgt[b][h=c*10+g][t] = bias[g*64+c] + sum_{i,tau} u * dk
__global__ void __launch_bounds__(256) k_conv(const float* __restrict__ hp,
                                              const float* __restrict__ dk,
                                              const float* __restrict__ dcls_b,
                                              float* __restrict__ ybcgt) {
    __shared__ float u[2 * 7 * 264];    // [pm][kk][264]
    __shared__ float dks[64 * 126];
    int tid = threadIdx.x;
    int t0 = blockIdx.x * 256;
    int g = blockIdx.y;
    int b = blockIdx.z;
    for (int idx = tid; idx < 8064; idx += 256) dks[idx] = dk[g * 8064 + idx];
    for (int idx = tid; idx < 3696; idx += 256) {
        int pm = idx / 1848;
        int rem = idx % 1848;
        int kk = rem / 264;
        int tt = rem % 264;
        int tg = t0 - 4 + tt;
        float v = (tg >= 0 && tg < 1000) ? hp[((size_t)(b * 34 + g * 3 + kk)) * 1000 + tg] : 0.f;
        u[idx] = pm ? fmaxf(-v, 0.f) : fmaxf(v, 0.f);
    }
    __syncthreads();
    int tl = tid & 63;
    int cg4 = tid >> 6;     // 0..3, c = cg4*16+ci
    float acc[16][4];
#pragma unroll
    for (int ci = 0; ci < 16; ++ci)
#pragma unroll
        for (int tq = 0; tq < 4; ++tq) acc[ci][tq] = 0.f;

    for (int i = 0; i < 14; ++i) {
#pragma unroll
        for (int tau = 0; tau < 9; ++tau) {
            const float* ub = u + i * 264 + tl + tau;
            float u0 = ub[0];
            float u1 = ub[64];
            float u2 = ub[128];
            float u3 = ub[192];
            const float* dp = dks + cg4 * 16 * 126 + i * 9 + tau;
#pragma unroll
            for (int ci = 0; ci < 16; ++ci) {
                float dv = dp[ci * 126];
                acc[ci][0] += u0 * dv;
                acc[ci][1] += u1 * dv;
                acc[ci][2] += u2 * dv;
                acc[ci][3] += u3 * dv;
            }
        }
    }
#pragma unroll
    for (int ci = 0; ci < 16; ++ci) {
        int c = cg4 * 16 + ci;
        float bias = dcls_b[g * 64 + c];
        size_t base = ((size_t)(b * 640 + c * 10 + g)) * 1000;
#pragma unroll
        for (int tq = 0; tq < 4; ++tq) {
            int t = t0 + tq * 64 + tl;
            if (t < 1000) ybcgt[base + t] = acc[ci][tq] + bias;
        }
    }
}

// ---------------------------------------------------------------------------
// K4: BN stats: per channel c sum & sumsq over (b,g,t). bnsum[0..63]=sum, [64..127]=sumsq
__global__ void k_bnstat(const float* __restrict__ ybcgt, float* __restrict__ bnsum) {
    int c = blockIdx.x / 10;
    int g = blockIdx.x % 10;
    int tid = threadIdx.x;
    float s = 0.f, q = 0.f;
    const float* base = ybcgt + ((size_t)(c * 10 + g)) * 1000;
    for (int b = 0; b < 32; ++b) {
        const float* p = base + (size_t)b * 640000;
        for (int t = tid; t < 1000; t += 256) {
            float v = p[t];
            s += v;
            q += v * v;
        }
    }
    for (int off = 1; off < 64; off <<= 1) {
        s += __shfl_xor(s, off);
        q += __shfl_xor(q, off);
    }
    __shared__ float rs[4], rq[4];
    if ((tid & 63) == 0) { rs[tid >> 6] = s; rq[tid >> 6] = q; }
    __syncthreads();
    if (tid == 0) {
        s = rs[0] + rs[1] + rs[2] + rs[3];
        q = rq[0] + rq[1] + rq[2] + rq[3];
        atomicAdd(&bnsum[c], s);
        atomicAdd(&bnsum[64 + c], q);
    }
}

// K5: BN finalize -> bnp[c]=scale, bnp[64+c]=shift
__global__ void k_bnfin(const float* __restrict__ bnsum, const float* __restrict__ gamma,
                        const float* __restrict__ beta, float* __restrict__ bnp) {
    int c = threadIdx.x;
    const float inv_n = 1.f / 320000.f;
    float mean = bnsum[c] * inv_n;
    float var = bnsum[64 + c] * inv_n - mean * mean;
    float sc = gamma[c] * rsqrtf(var + 1e-5f);
    bnp[c] = sc;
    bnp[64 + c] = beta[c] - mean * sc;
}

// ---------------------------------------------------------------------------
// K6: fused transpose + BN + sigmoid: seq[(t*32+b)*640 + h] = sigmoid(scale*y + shift) (fp16)
__global__ void k_tr(const float* __restrict__ ybcgt, const float* __restrict__ bnp,
                     __half* __restrict__ seq) {
    __shared__ float tile[64 * 65];
    int tid = threadIdx.x;
    int tt0 = blockIdx.x * 64;
    int h0 = blockIdx.y * 64;
    int b = blockIdx.z;
    int tx = tid & 63;
    int ty = tid >> 6;
#pragma unroll
    for (int r = 0; r < 16; ++r) {
        int hh = r * 4 + ty;
        int t = tt0 + tx;
        float v = (t < 1000) ? ybcgt[((size_t)(b * 640 + h0 + hh)) * 1000 + t] : 0.f;
        int c = (h0 + hh) / 10;
        float sarg = bnp[c] * v + bnp[64 + c];
        tile[hh * 65 + tx] = 1.f / (1.f + __expf(-sarg));
    }
    __syncthreads();
#pragma unroll
    for (int r = 0; r < 16; ++r) {
        int t = tt0 + r * 4 + ty;
        if (t < 1000)
            seq[((size_t)t * 32 + b) * 640 + h0 + tx] = __float2half(tile[tx * 65 + r * 4 + ty]);
    }
}

// ---------------------------------------------------------------------------
// K7: x_proj GEMM (r7 version, passed): BM=BN=128, BK=8, 256 thr, 8x8 micro,
// 16 NAMED f4 accs; __launch_bounds__(256,4); Bs swizzled to break bank alias.
#define BCOL(c) ((c) + (((c) >> 5) << 2))
__global__ void __launch_bounds__(256, 4) k_gemm(const __half* __restrict__ A,
                                                 const float* __restrict__ W,
                                                 const float* __restrict__ bih,
                                                 __half* __restrict__ C) {
    __shared__ float As[8][128];
    __shared__ float Bs[8][140];
    int tid = threadIdx.x;
    int n0 = blockIdx.x * 128;
    int m0 = blockIdx.y * 128;
    int tx = tid & 15;          // n-subtile: cols n0 + tx*8 .. +7
    int ty = tid >> 4;          // m-subtile: rows m0 + ty*8 .. +7
    int lm = tid >> 1;
    int lk4 = (tid & 1) * 4;
    int lmB = BCOL(lm);
    const int bc0 = BCOL(tx * 8);
    const int bc1 = BCOL(tx * 8 + 4);
    const __half* Ab = A + (size_t)(m0 + lm) * 640 + lk4;
    const float* Bb = W + (size_t)(n0 + lm) * 640 + lk4;

    f4 c0a = {0,0,0,0}, c0b = {0,0,0,0}, c1a = {0,0,0,0}, c1b = {0,0,0,0};
    f4 c2a = {0,0,0,0}, c2b = {0,0,0,0}, c3a = {0,0,0,0}, c3b = {0,0,0,0};
    f4 c4a = {0,0,0,0}, c4b = {0,0,0,0}, c5a = {0,0,0,0}, c5b = {0,0,0,0};
    f4 c6a = {0,0,0,0}, c6b = {0,0,0,0}, c7a = {0,0,0,0}, c7b = {0,0,0,0};

    for (int kt = 0; kt < 80; ++kt) {
        float2 araw = *(const float2*)(Ab + (size_t)kt * 8);   // 4 halves
        const __half2* ah = (const __half2*)&araw;
        float2 a01 = __half22float2(ah[0]);
        float2 a23 = __half22float2(ah[1]);
        float4 bv = *(const float4*)(Bb + (size_t)kt * 8);
        __syncthreads();
        As[lk4 + 0][lm] = a01.x; As[lk4 + 1][lm] = a01.y;
        As[lk4 + 2][lm] = a23.x; As[lk4 + 3][lm] = a23.y;
        Bs[lk4 + 0][lmB] = bv.x; Bs[lk4 + 1][lmB] = bv.y;
        Bs[lk4 + 2][lmB] = bv.z; Bs[lk4 + 3][lmB] = bv.w;
        __syncthreads();
#pragma unroll
        for (int kk = 0; kk < 8; ++kk) {
            f4 blo = *(const f4*)&Bs[kk][bc0];
            f4 bhi = *(const f4*)&Bs[kk][bc1];
            f4 alo = *(const f4*)&As[kk][ty * 8];
            f4 ahi = *(const f4*)&As[kk][ty * 8 + 4];
            c0a += alo.x * blo; c0b += alo.x * bhi;
            c1a += alo.y * blo; c1b += alo.y * bhi;
            c2a += alo.z * blo; c2b += alo.z * bhi;
            c3a += alo.w * blo; c3b += alo.w * bhi;
            c4a += ahi.x * blo; c4b += ahi.x * bhi;
            c5a += ahi.y * blo; c5b += ahi.y * bhi;
            c6a += ahi.z * blo; c6b += ahi.z * bhi;
            c7a += ahi.w * blo; c7b += ahi.w * bhi;
        }
    }
    f4 bblo = *(const f4*)&bih[n0 + tx * 8];
    f4 bbhi = *(const f4*)&bih[n0 + tx * 8 + 4];
    union { __half h[8]; float4 v; } ob;
#define STORE_ROW(i, ra, rb)                                                     \
    {                                                                            \
        f4 lo = ra + bblo; f4 hi = rb + bbhi;                                    \
        ob.h[0] = __float2half(lo.x); ob.h[1] = __float2half(lo.y);              \
        ob.h[2] = __float2half(lo.z); ob.h[3] = __float2half(lo.w);              \
        ob.h[4] = __float2half(hi.x); ob.h[5] = __float2half(hi.y);              \
        ob.h[6] = __float2half(hi.z); ob.h[7] = __float2half(hi.w);              \
        *(float4*)&C[(size_t)(m0 + ty * 8 + i) * 1920 + n0 + tx * 8] = ob.v;     \
    }
    STORE_ROW(0, c0a, c0b) STORE_ROW(1, c1a, c1b) STORE_ROW(2, c2a, c2b)
    STORE_ROW(3, c3a, c3b) STORE_ROW(4, c4a, c4b) STORE_ROW(5, c5a, c5b)
    STORE_ROW(6, c6a, c6b) STORE_ROW(7, c7a, c7b)
#undef STORE_ROW
}

// ---------------------------------------------------------------------------
// K8: persistent GRU — EXACT round-4 submission (best measured: 6.70ms steady).
// L3-direct AGENT relaxed atomics (u64 = 2 packed fp32), batched 2x20 staging,
// stride-32 h_lds, #pragma unroll 8 compute, 8-line monotone fetch_add barrier.
// (W-register-hoist variants failed correctness twice — do not reintroduce.)
__global__ void __launch_bounds__(256, 1) k_gru(const __half* __restrict__ xp,
                                                const float* __restrict__ Whh,
                                                const float* __restrict__ bhh,
                                                const float* __restrict__ fcw,
                                                u64* __restrict__ hgu,
                                                float* __restrict__ fcpart,
                                                unsigned* __restrict__ bar) {
    __shared__ __align__(16) float w_lds[640 * 16];   // [k][jj*4+g], g<3  (40960 B)
    __shared__ __align__(16) float h_lds[640 * 32];   // full h staging    (81920 B)
    float* red = h_lds;            // overlay after compute: [w][16][24] = 1536 floats
    float* fcred = h_lds + 1536;   // 128 floats

    const int tid = threadIdx.x;
    const int blk = blockIdx.x;
    const int j0 = blk * 4;
    const int ksx = tid >> 4;
    const int jj = (tid >> 2) & 3;
    const int bg = tid & 3;
    const int lane = tid & 63;
    const int wid = tid >> 6;

    // Load the block's 12 W_hh rows into LDS once (persists across all steps)
    for (int r = 0; r < 12; ++r) {
        int wjj = r / 3, wg = r % 3;
        const float* src = Whh + (size_t)(wg * 640 + j0 + wjj) * 640;
        for (int k = tid; k < 640; k += 256) w_lds[k * 16 + wjj * 4 + wg] = src[k];
    }
    float bh_r = 0.f, bh_z = 0.f, bh_n = 0.f, fw = 0.f, hold = 0.f;
    if (tid < 128) {
        int fj = j0 + (tid >> 5);
        bh_r = bhh[fj];
        bh_z = bhh[640 + fj];
        bh_n = bhh[1280 + fj];
        fw = fcw[fj];
    }
    __syncthreads();

    // preload xp for t=0 (plain cached loads)
    float xr = 0.f, xz = 0.f, xn = 0.f;
    if (tid < 128) {
        const __half* xpt = xp + (size_t)(tid & 31) * 1920;
        int j = j0 + (tid >> 5);
        xr = __half2float(xpt[j]);
        xz = __half2float(xpt[640 + j]);
        xn = __half2float(xpt[1280 + j]);
    }

    for (int t = 0; t < 1000; ++t) {
        const u64* hcur = hgu + (size_t)(t & 1) * 10240;
        u64* hnxt = hgu + (size_t)((t + 1) & 1) * 10240;

        // batched h staging: 2 chunks of 20 independent L3 atomic loads
#pragma unroll
        for (int c = 0; c < 2; ++c) {
            u64 rr[20];
#pragma unroll
            for (int i = 0; i < 20; ++i)
                rr[i] = __hip_atomic_load(&hcur[c * 5120 + i * 256 + tid],
                                          __ATOMIC_RELAXED, __HIP_MEMORY_SCOPE_AGENT);
#pragma unroll
            for (int i = 0; i < 20; ++i) {
                int e = c * 5120 + i * 256 + tid;   // e = k*16 + b/2
                union { u64 u; float2 f; } pk;
                pk.u = rr[i];
                *(float2*)&h_lds[(e >> 4) * 32 + (e & 15) * 2] = pk.f;
            }
        }
        __syncthreads();

        // prefetch xp for step t+1 (overlaps with compute below)
        float nxr = 0.f, nxz = 0.f, nxn = 0.f;
        if (t + 1 < 1000 && tid < 128) {
            const __half* xpt = xp + (size_t)(t + 1) * 61440 + (size_t)(tid & 31) * 1920;
            int j = j0 + (tid >> 5);
            nxr = __half2float(xpt[j]);
            nxz = __half2float(xpt[640 + j]);
            nxn = __half2float(xpt[1280 + j]);
        }

        float a0[8], a1[8], a2[8];
#pragma unroll
        for (int i = 0; i < 8; ++i) { a0[i] = 0.f; a1[i] = 0.f; a2[i] = 0.f; }

#pragma unroll 8
        for (int ii = 0; ii < 40; ++ii) {
            int k = ii * 16 + ksx;
            float4 wv = *(const float4*)(w_lds + k * 16 + jj * 4);
            float4 h0 = *(const float4*)(h_lds + k * 32 + bg * 8);
            float4 h1 = *(const float4*)(h_lds + k * 32 + bg * 8 + 4);
            a0[0] += wv.x * h0.x; a0[1] += wv.x * h0.y; a0[2] += wv.x * h0.z; a0[3] += wv.x * h0.w;
            a0[4] += wv.x * h1.x; a0[5] += wv.x * h1.y; a0[6] += wv.x * h1.z; a0[7] += wv.x * h1.w;
            a1[0] += wv.y * h0.x; a1[1] += wv.y * h0.y; a1[2] += wv.y * h0.z; a1[3] += wv.y * h0.w;
            a1[4] += wv.y * h1.x; a1[5] += wv.y * h1.y; a1[6] += wv.y * h1.z; a1[7] += wv.y * h1.w;
            a2[0] += wv.z * h0.x; a2[1] += wv.z * h0.y; a2[2] += wv.z * h0.z; a2[3] += wv.z * h0.w;
            a2[4] += wv.z * h1.x; a2[5] += wv.z * h1.y; a2[6] += wv.z * h1.z; a2[7] += wv.z * h1.w;
        }
        // reduce over 4 ksx within each wave (lane distance 16, 32)
#pragma unroll
        for (int i = 0; i < 8; ++i) {
            a0[i] += __shfl_xor(a0[i], 16); a0[i] += __shfl_xor(a0[i], 32);
            a1[i] += __shfl_xor(a1[i], 16); a1[i] += __shfl_xor(a1[i], 32);
            a2[i] += __shfl_xor(a2[i], 16); a2[i] += __shfl_xor(a2[i], 32);
        }
        __syncthreads();   // h_lds reads done; safe to reuse as 'red'
        if (lane < 16) {
            float* rp = red + (wid * 16 + lane) * 24;
#pragma unroll
            for (int i = 0; i < 8; ++i) { rp[i] = a0[i]; rp[8 + i] = a1[i]; rp[16 + i] = a2[i]; }
        }
        __syncthreads();
        if (tid < 128) {
            int fb = tid & 31;
            int rr_ = ((tid >> 5) << 2) | (fb >> 3);
            int bif = fb & 7;
            float hr = bh_r, hz = bh_z, hn = bh_n;
#pragma unroll
            for (int w2 = 0; w2 < 4; ++w2) {
                const float* rp = red + (w2 * 16 + rr_) * 24;
                hr += rp[bif];
                hz += rp[8 + bif];
                hn += rp[16 + bif];
            }
            int j = j0 + (tid >> 5);
            float r_ = 1.f / (1.f + __expf(-(xr + hr)));
            float z_ = 1.f / (1.f + __expf(-(xz + hz)));
            float pre = xn + r_ * hn;
            float e2 = __expf(-2.f * fabsf(pre));
            float tn = (1.f - e2) / (1.f + e2);
            float n_ = (pre >= 0.f) ? tn : -tn;
            float hnew = (1.f - z_) * n_ + z_ * hold;
            hold = hnew;
            // pack pair (fb even gets fb, fb+1) and store L3-direct
            float other = __shfl_xor(hnew, 1);
            if ((fb & 1) == 0) {
                union { u64 u; float2 f; } pk;
                pk.f.x = hnew; pk.f.y = other;
                __hip_atomic_store(&hnxt[j * 16 + (fb >> 1)], pk.u,
                                   __ATOMIC_RELAXED, __HIP_MEMORY_SCOPE_AGENT);
            }
            fcred[tid] = hnew * fw;
            // drain this wave's h stores to L3 before the arrival add below
            __builtin_amdgcn_s_waitcnt(0);
        }
        xr = nxr; xz = nxz; xn = nxn;
        __syncthreads();
        if (tid < 32) {
            float s = fcred[tid] + fcred[32 + tid] + fcred[64 + tid] + fcred[96 + tid];
            __hip_atomic_store(&fcpart[(size_t)blk * 32000 + t * 32 + tid], s,
                               __ATOMIC_RELAXED, __HIP_MEMORY_SCOPE_AGENT);
        }

        // ---- monotone 8-line grid barrier (no fences, no reset) ----
        if (tid == 0) {
            unsigned target = 160u * (unsigned)(t + 1);
            __hip_atomic_fetch_add(&bar[(blk & 7) * 32], 1u,
                                   __ATOMIC_RELAXED, __HIP_MEMORY_SCOPE_AGENT);
            for (;;) {
                unsigned s = 0;
#pragma unroll
                for (int i = 0; i < 8; ++i)
                    s += __hip_atomic_load(&bar[i * 32], __ATOMIC_RELAXED,
                                           __HIP_MEMORY_SCOPE_AGENT);
                if (s >= target) break;
                __builtin_amdgcn_s_sleep(1);
            }
        }
        __syncthreads();
        __atomic_signal_fence(__ATOMIC_SEQ_CST);   // compiler-only ordering
    }
}

// ---------------------------------------------------------------------------
// K9: final fc reduction: out[b*1000+t] = fc_b + sum_blk fcpart[blk][t][b]
__global__ void k_fc(const float* __restrict__ fcpart, const float* __restrict__ fcb,
                     float* __restrict__ out) {
    int gid = blockIdx.x * 256 + threadIdx.x;  // < 32000
    int t = gid >> 5;
    int b = gid & 31;
    float s = fcb[0];
    for (int blk = 0; blk < 160; ++blk) s += fcpart[(size_t)blk * 32000 + t * 32 + b];
    out[(size_t)b * 1000 + t] = s;
}

// ---------------------------------------------------------------------------
extern "C" void kernel_launch(void* const* d_in, const int* in_sizes, int n_in,
                              void* d_out, int out_size, void* d_ws, size_t ws_size,
                              hipStream_t stream) {
    const float* x      = (const float*)d_in[0];
    const float* a_vals = (const float*)d_in[1];
    const float* w_vals = (const float*)d_in[2];
    const float* dcls_w = (const float*)d_in[3];
    const float* dcls_p = (const float*)d_in[4];
    const float* dcls_b = (const float*)d_in[5];
    const float* gamma  = (const float*)d_in[6];
    const float* beta   = (const float*)d_in[7];
    const float* W_ih   = (const float*)d_in[8];
    const float* W_hh   = (const float*)d_in[9];
    const float* b_ih   = (const float*)d_in[10];
    const float* b_hh   = (const float*)d_in[11];
    const float* fc_w   = (const float*)d_in[12];
    const float* fc_b   = (const float*)d_in[13];
    char* w = (char*)d_ws;

    // ws layout (bytes). Peak total: ~164.0 MB.
    //   [0, 122,880,000)           xpH   fp16 32000x1920  -- phase D
    //       overlay [0, 81,920,000)        ybcgt fp32     -- phases A-B (dead before GEMM)
    //   [122,880,000, 163,840,000) seqH  fp16 32000x640   -- phases B-C
    //       overlay: hp fp32 + dk fp32  -- phase A;  fcpart fp32 -- phase D
    //   [163,840,000, 164,003,840) hgu   u64 2x10240 (h dbuf, fp32 pair per u64)
    //   [164,003,840, 164,004,352) bnsum fp32 128
    //   [164,004,352, 164,004,864) bnp   fp32 128
    //   [164,004,864, 164,005,888) bar   u32 8x32 (128B-spaced monotone counters)
    __half* xpH    = (__half*)(w);
    float* ybcgt   = (float*)(w);
    __half* seqH   = (__half*)(w + 122880000);
    float* hp      = (float*)(w + 122880000);
    float* dk      = (float*)(w + 122880000 + 4352000);
    float* fcpart  = (float*)(w + 122880000);
    u64* hgu       = (u64*)(w + 163840000);
    float* bnsum   = (float*)(w + 164003840);
    unsigned* bar  = (unsigned*)(w + 164004864);

    // zero h0 double-buffer + bn accumulators + bnp + barrier counters (contiguous tail)
    hipMemsetAsync(w + 163840000, 0, 165888, stream);

    k_dk<<<dim3(315), dim3(256), 0, stream>>>(dcls_w, dcls_p, dk);
    k_ema<<<dim3(1088), dim3(256), 0, stream>>>(x, a_vals, w_vals, hp);
    k_conv<<<dim3(4, 10, 32), dim3(256), 0, stream>>>(hp, dk, dcls_b, ybcgt);
    k_bnstat<<<dim3(640), dim3(256), 0, stream>>>(ybcgt, bnsum);
    k_bnfin<<<dim3(1), dim3(64), 0, stream>>>(bnsum, gamma, beta, (float*)(w + 164004352));
    k_tr<<<dim3(16, 10, 32), dim3(256), 0, stream>>>(ybcgt, (float*)(w + 164004352), seqH);
    k_gemm<<<dim3(15, 250), dim3(256), 0, stream>>>(seqH, W_ih, b_ih, xpH);

    {
        const __half* xp_a = xpH;
        void* args[] = {(void*)&xp_a, (void*)&W_hh, (void*)&b_hh, (void*)&fc_w,
                        (void*)&hgu, (void*)&fcpart, (void*)&bar};
        hipLaunchCooperativeKernel((void*)k_gru, dim3(160), dim3(256), args, 0, stream);
    }

    k_fc<<<dim3(125), dim3(256), 0, stream>>>(fcpart, fc_b, (float*)d_out);
}

// Round 11
// 7225.327 us; speedup vs baseline: 1.2617x; 1.0298x over previous
//
#include <hip/hip_runtime.h>
#include <hip/hip_fp16.h>
#include <cstdint>

typedef float f4 __attribute__((ext_vector_type(4)));
typedef unsigned long long u64;

// Problem constants
// B=32, F=34, T=1000, K=7, S=3, F_DOWN=10, C=64, H=640, 3H=1920, T_MAX=9, PAD=4, MS_KS=200

// ---------------------------------------------------------------------------
// K1: build DCLS kernel dk[h][i][tau], h<640, i<14, tau<9
__global__ void k_dk(const float* __restrict__ dcls_w, const float* __restrict__ dcls_p,
                     float* __restrict__ dk) {
    int idx = blockIdx.x * 256 + threadIdx.x;
    if (idx >= 640 * 126) return;
    int h = idx / 126;
    int r = idx % 126;
    int i = r / 9;
    int tau = r % 9;
    float p = dcls_p[h * 14 + i];
    p = fminf(fmaxf(p, 0.f), 8.f);
    float tri = fmaxf(1.f - fabsf((float)tau - p), 0.f);
    dk[idx] = dcls_w[h * 14 + i] * tri;
}

// ---------------------------------------------------------------------------
// K2: EMA lowpass (200-tap truncated, exact) + highpass. hp[b][f][t]
__global__ void k_ema(const float* __restrict__ x, const float* __restrict__ a_vals,
                      const float* __restrict__ w_vals, float* __restrict__ hp) {
    __shared__ float xr[1024];
    int bf = blockIdx.x;               // b*34+f
    int f = bf % 34;
    int tid = threadIdx.x;
    const float* xs = x + (size_t)bf * 1000;
    for (int i = tid; i < 1000; i += 256) xr[i] = xs[i];
    for (int i = 1000 + tid; i < 1024; i += 256) xr[i] = 0.f;
    __syncthreads();
    float a = a_vals[f], wv = w_vals[f];
    float om = 1.f - a;
    int t1 = tid, t2 = tid + 256, t3 = tid + 512, t4 = tid + 768;
    bool v4 = (t4 < 1000);
    float a0 = 0.f, a1 = 0.f, a2 = 0.f, a3 = 0.f;
    float coef = a;
    for (int k = 0; k < 200; ++k) {
        a0 += (k <= t1 ? xr[t1 - k] : 0.f) * coef;
        a1 += xr[t2 - k] * coef;
        a2 += xr[t3 - k] * coef;
        a3 += (v4 ? xr[t4 - k] : 0.f) * coef;
        coef *= om;
    }
    float* op = hp + (size_t)bf * 1000;
    op[t1] = xr[t1] - wv * a0;
    op[t2] = xr[t2] - wv * a1;
    op[t3] = xr[t3] - wv * a2;
    if (v4) op[t4] = xr[t4] - wv * a3;
}

// ---------------------------------------------------------------------------
// K3: DCLS grouped conv. ybcgt[b][h=c*10+g][t] = bias[g*64+c] + sum_{i,tau} u * dk
__global__ void __launch_bounds__(256) k_conv(const float* __restrict__ hp,
                                              const float* __restrict__ dk,
                                              const float* __restrict__ dcls_b,
                                              float* __restrict__ ybcgt) {
    __shared__ float u[2 * 7 * 264];    // [pm][kk][264]
    __shared__ float dks[64 * 126];
    int tid = threadIdx.x;
    int t0 = blockIdx.x * 256;
    int g = blockIdx.y;
    int b = blockIdx.z;
    for (int idx = tid; idx < 8064; idx += 256) dks[idx] = dk[g * 8064 + idx];
    for (int idx = tid; idx < 3696; idx += 256) {
        int pm = idx / 1848;
        int rem = idx % 1848;
        int kk = rem / 264;
        int tt = rem % 264;
        int tg = t0 - 4 + tt;
        float v = (tg >= 0 && tg < 1000) ? hp[((size_t)(b * 34 + g * 3 + kk)) * 1000 + tg] : 0.f;
        u[idx] = pm ? fmaxf(-v, 0.f) : fmaxf(v, 0.f);
    }
    __syncthreads();
    int tl = tid & 63;
    int cg4 = tid >> 6;     // 0..3, c = cg4*16+ci
    float acc[16][4];
#pragma unroll
    for (int ci = 0; ci < 16; ++ci)
#pragma unroll
        for (int tq = 0; tq < 4; ++tq) acc[ci][tq] = 0.f;

    for (int i = 0; i < 14; ++i) {
#pragma unroll
        for (int tau = 0; tau < 9; ++tau) {
            const float* ub = u + i * 264 + tl + tau;
            float u0 = ub[0];
            float u1 = ub[64];
            float u2 = ub[128];
            float u3 = ub[192];
            const float* dp = dks + cg4 * 16 * 126 + i * 9 + tau;
#pragma unroll
            for (int ci = 0; ci < 16; ++ci) {
                float dv = dp[ci * 126];
                acc[ci][0] += u0 * dv;
                acc[ci][1] += u1 * dv;
                acc[ci][2] += u2 * dv;
                acc[ci][3] += u3 * dv;
            }
        }
    }
#pragma unroll
    for (int ci = 0; ci < 16; ++ci) {
        int c = cg4 * 16 + ci;
        float bias = dcls_b[g * 64 + c];
        size_t base = ((size_t)(b * 640 + c * 10 + g)) * 1000;
#pragma unroll
        for (int tq = 0; tq < 4; ++tq) {
            int t = t0 + tq * 64 + tl;
            if (t < 1000) ybcgt[base + t] = acc[ci][tq] + bias;
        }
    }
}

// ---------------------------------------------------------------------------
// K4: BN stats: per channel c sum & sumsq over (b,g,t). bnsum[0..63]=sum, [64..127]=sumsq
__global__ void k_bnstat(const float* __restrict__ ybcgt, float* __restrict__ bnsum) {
    int c = blockIdx.x / 10;
    int g = blockIdx.x % 10;
    int tid = threadIdx.x;
    float s = 0.f, q = 0.f;
    const float* base = ybcgt + ((size_t)(c * 10 + g)) * 1000;
    for (int b = 0; b < 32; ++b) {
        const float* p = base + (size_t)b * 640000;
        for (int t = tid; t < 1000; t += 256) {
            float v = p[t];
            s += v;
            q += v * v;
        }
    }
    for (int off = 1; off < 64; off <<= 1) {
        s += __shfl_xor(s, off);
        q += __shfl_xor(q, off);
    }
    __shared__ float rs[4], rq[4];
    if ((tid & 63) == 0) { rs[tid >> 6] = s; rq[tid >> 6] = q; }
    __syncthreads();
    if (tid == 0) {
        s = rs[0] + rs[1] + rs[2] + rs[3];
        q = rq[0] + rq[1] + rq[2] + rq[3];
        atomicAdd(&bnsum[c], s);
        atomicAdd(&bnsum[64 + c], q);
    }
}

// K5: BN finalize -> bnp[c]=scale, bnp[64+c]=shift
__global__ void k_bnfin(const float* __restrict__ bnsum, const float* __restrict__ gamma,
                        const float* __restrict__ beta, float* __restrict__ bnp) {
    int c = threadIdx.x;
    const float inv_n = 1.f / 320000.f;
    float mean = bnsum[c] * inv_n;
    float var = bnsum[64 + c] * inv_n - mean * mean;
    float sc = gamma[c] * rsqrtf(var + 1e-5f);
    bnp[c] = sc;
    bnp[64 + c] = beta[c] - mean * sc;
}

// ---------------------------------------------------------------------------
// K6: fused transpose + BN + sigmoid: seq[(t*32+b)*640 + h] = sigmoid(scale*y + shift) (fp16)
__global__ void k_tr(const float* __restrict__ ybcgt, const float* __restrict__ bnp,
                     __half* __restrict__ seq) {
    __shared__ float tile[64 * 65];
    int tid = threadIdx.x;
    int tt0 = blockIdx.x * 64;
    int h0 = blockIdx.y * 64;
    int b = blockIdx.z;
    int tx = tid & 63;
    int ty = tid >> 6;
#pragma unroll
    for (int r = 0; r < 16; ++r) {
        int hh = r * 4 + ty;
        int t = tt0 + tx;
        float v = (t < 1000) ? ybcgt[((size_t)(b * 640 + h0 + hh)) * 1000 + t] : 0.f;
        int c = (h0 + hh) / 10;
        float sarg = bnp[c] * v + bnp[64 + c];
        tile[hh * 65 + tx] = 1.f / (1.f + __expf(-sarg));
    }
    __syncthreads();
#pragma unroll
    for (int r = 0; r < 16; ++r) {
        int t = tt0 + r * 4 + ty;
        if (t < 1000)
            seq[((size_t)t * 32 + b) * 640 + h0 + tx] = __float2half(tile[tx * 65 + r * 4 + ty]);
    }
}

// ---------------------------------------------------------------------------
// K7: x_proj GEMM (r7/r10 version, passing): BM=BN=128, BK=8, 256 thr, 8x8 micro,
// 16 NAMED f4 accs; __launch_bounds__(256,4); Bs swizzled to break bank alias.
#define BCOL(c) ((c) + (((c) >> 5) << 2))
__global__ void __launch_bounds__(256, 4) k_gemm(const __half* __restrict__ A,
                                                 const float* __restrict__ W,
                                                 const float* __restrict__ bih,
                                                 __half* __restrict__ C) {
    __shared__ float As[8][128];
    __shared__ float Bs[8][140];
    int tid = threadIdx.x;
    int n0 = blockIdx.x * 128;
    int m0 = blockIdx.y * 128;
    int tx = tid & 15;          // n-subtile: cols n0 + tx*8 .. +7
    int ty = tid >> 4;          // m-subtile: rows m0 + ty*8 .. +7
    int lm = tid >> 1;
    int lk4 = (tid & 1) * 4;
    int lmB = BCOL(lm);
    const int bc0 = BCOL(tx * 8);
    const int bc1 = BCOL(tx * 8 + 4);
    const __half* Ab = A + (size_t)(m0 + lm) * 640 + lk4;
    const float* Bb = W + (size_t)(n0 + lm) * 640 + lk4;

    f4 c0a = {0,0,0,0}, c0b = {0,0,0,0}, c1a = {0,0,0,0}, c1b = {0,0,0,0};
    f4 c2a = {0,0,0,0}, c2b = {0,0,0,0}, c3a = {0,0,0,0}, c3b = {0,0,0,0};
    f4 c4a = {0,0,0,0}, c4b = {0,0,0,0}, c5a = {0,0,0,0}, c5b = {0,0,0,0};
    f4 c6a = {0,0,0,0}, c6b = {0,0,0,0}, c7a = {0,0,0,0}, c7b = {0,0,0,0};

    for (int kt = 0; kt < 80; ++kt) {
        float2 araw = *(const float2*)(Ab + (size_t)kt * 8);   // 4 halves
        const __half2* ah = (const __half2*)&araw;
        float2 a01 = __half22float2(ah[0]);
        float2 a23 = __half22float2(ah[1]);
        float4 bv = *(const float4*)(Bb + (size_t)kt * 8);
        __syncthreads();
        As[lk4 + 0][lm] = a01.x; As[lk4 + 1][lm] = a01.y;
        As[lk4 + 2][lm] = a23.x; As[lk4 + 3][lm] = a23.y;
        Bs[lk4 + 0][lmB] = bv.x; Bs[lk4 + 1][lmB] = bv.y;
        Bs[lk4 + 2][lmB] = bv.z; Bs[lk4 + 3][lmB] = bv.w;
        __syncthreads();
#pragma unroll
        for (int kk = 0; kk < 8; ++kk) {
            f4 blo = *(const f4*)&Bs[kk][bc0];
            f4 bhi = *(const f4*)&Bs[kk][bc1];
            f4 alo = *(const f4*)&As[kk][ty * 8];
            f4 ahi = *(const f4*)&As[kk][ty * 8 + 4];
            c0a += alo.x * blo; c0b += alo.x * bhi;
            c1a += alo.y * blo; c1b += alo.y * bhi;
            c2a += alo.z * blo; c2b += alo.z * bhi;
            c3a += alo.w * blo; c3b += alo.w * bhi;
            c4a += ahi.x * blo; c4b += ahi.x * bhi;
            c5a += ahi.y * blo; c5b += ahi.y * bhi;
            c6a += ahi.z * blo; c6b += ahi.z * bhi;
            c7a += ahi.w * blo; c7b += ahi.w * bhi;
        }
    }
    f4 bblo = *(const f4*)&bih[n0 + tx * 8];
    f4 bbhi = *(const f4*)&bih[n0 + tx * 8 + 4];
    union { __half h[8]; float4 v; } ob;
#define STORE_ROW(i, ra, rb)                                                     \
    {                                                                            \
        f4 lo = ra + bblo; f4 hi = rb + bbhi;                                    \
        ob.h[0] = __float2half(lo.x); ob.h[1] = __float2half(lo.y);              \
        ob.h[2] = __float2half(lo.z); ob.h[3] = __float2half(lo.w);              \
        ob.h[4] = __float2half(hi.x); ob.h[5] = __float2half(hi.y);              \
        ob.h[6] = __float2half(hi.z); ob.h[7] = __float2half(hi.w);              \
        *(float4*)&C[(size_t)(m0 + ty * 8 + i) * 1920 + n0 + tx * 8] = ob.v;     \
    }
    STORE_ROW(0, c0a, c0b) STORE_ROW(1, c1a, c1b) STORE_ROW(2, c2a, c2b)
    STORE_ROW(3, c3a, c3b) STORE_ROW(4, c4a, c4b) STORE_ROW(5, c5a, c5b)
    STORE_ROW(6, c6a, c6b) STORE_ROW(7, c7a, c7b)
#undef STORE_ROW
}

// ---------------------------------------------------------------------------
// K8: persistent GRU = round-10 baseline with ONE change: fp16 h exchange
// (4 halves per u64 -> 20 staging loads instead of 40; halves L3 broadcast BW).
// Unpack stores are f4 at h_lds[(e>>3)*32 + (e&7)*4] -> 16B-aligned (stride 32).
// Pack/store code is r6's correctness-proven sequence. Everything else identical:
// stride-32 h_lds, #pragma unroll 8 compute, 8-line monotone fetch_add barrier.
__global__ void __launch_bounds__(256, 1) k_gru(const __half* __restrict__ xp,
                                                const float* __restrict__ Whh,
                                                const float* __restrict__ bhh,
                                                const float* __restrict__ fcw,
                                                u64* __restrict__ hgu,
                                                float* __restrict__ fcpart,
                                                unsigned* __restrict__ bar) {
    __shared__ __align__(16) float w_lds[640 * 16];   // [k][jj*4+g], g<3  (40960 B)
    __shared__ __align__(16) float h_lds[640 * 32];   // full h staging    (81920 B)
    float* red = h_lds;            // overlay after compute: [w][16][24] = 1536 floats
    float* fcred = h_lds + 1536;   // 128 floats

    const int tid = threadIdx.x;
    const int blk = blockIdx.x;
    const int j0 = blk * 4;
    const int ksx = tid >> 4;
    const int jj = (tid >> 2) & 3;
    const int bg = tid & 3;
    const int lane = tid & 63;
    const int wid = tid >> 6;

    // Load the block's 12 W_hh rows into LDS once (persists across all steps)
    for (int r = 0; r < 12; ++r) {
        int wjj = r / 3, wg = r % 3;
        const float* src = Whh + (size_t)(wg * 640 + j0 + wjj) * 640;
        for (int k = tid; k < 640; k += 256) w_lds[k * 16 + wjj * 4 + wg] = src[k];
    }
    float bh_r = 0.f, bh_z = 0.f, bh_n = 0.f, fw = 0.f, hold = 0.f;
    if (tid < 128) {
        int fj = j0 + (tid >> 5);
        bh_r = bhh[fj];
        bh_z = bhh[640 + fj];
        bh_n = bhh[1280 + fj];
        fw = fcw[fj];
    }
    __syncthreads();

    // preload xp for t=0 (plain cached loads)
    float xr = 0.f, xz = 0.f, xn = 0.f;
    if (tid < 128) {
        const __half* xpt = xp + (size_t)(tid & 31) * 1920;
        int j = j0 + (tid >> 5);
        xr = __half2float(xpt[j]);
        xz = __half2float(xpt[640 + j]);
        xn = __half2float(xpt[1280 + j]);
    }

    for (int t = 0; t < 1000; ++t) {
        const u64* hcur = hgu + (size_t)(t & 1) * 5120;
        u64* hnxt = hgu + (size_t)((t + 1) & 1) * 5120;

        // batched h staging: 20 independent L3 atomic u64 loads (4 fp16 each)
        u64 rr[20];
#pragma unroll
        for (int i = 0; i < 20; ++i)
            rr[i] = __hip_atomic_load(&hcur[i * 256 + tid],
                                      __ATOMIC_RELAXED, __HIP_MEMORY_SCOPE_AGENT);
#pragma unroll
        for (int i = 0; i < 20; ++i) {
            int e = i * 256 + tid;             // e = k*8 + b/4
            union { u64 u; __half2 h2[2]; } pk;
            pk.u = rr[i];
            float2 lo = __half22float2(pk.h2[0]);
            float2 hi = __half22float2(pk.h2[1]);
            f4 v = {lo.x, lo.y, hi.x, hi.y};
            *(f4*)&h_lds[(e >> 3) * 32 + (e & 7) * 4] = v;   // 16B-aligned (stride 32)
        }
        __syncthreads();

        // prefetch xp for step t+1 (overlaps with compute below)
        float nxr = 0.f, nxz = 0.f, nxn = 0.f;
        if (t + 1 < 1000 && tid < 128) {
            const __half* xpt = xp + (size_t)(t + 1) * 61440 + (size_t)(tid & 31) * 1920;
            int j = j0 + (tid >> 5);
            nxr = __half2float(xpt[j]);
            nxz = __half2float(xpt[640 + j]);
            nxn = __half2float(xpt[1280 + j]);
        }

        float a0[8], a1[8], a2[8];
#pragma unroll
        for (int i = 0; i < 8; ++i) { a0[i] = 0.f; a1[i] = 0.f; a2[i] = 0.f; }

#pragma unroll 8
        for (int ii = 0; ii < 40; ++ii) {
            int k = ii * 16 + ksx;
            float4 wv = *(const float4*)(w_lds + k * 16 + jj * 4);
            float4 h0 = *(const float4*)(h_lds + k * 32 + bg * 8);
            float4 h1 = *(const float4*)(h_lds + k * 32 + bg * 8 + 4);
            a0[0] += wv.x * h0.x; a0[1] += wv.x * h0.y; a0[2] += wv.x * h0.z; a0[3] += wv.x * h0.w;
            a0[4] += wv.x * h1.x; a0[5] += wv.x * h1.y; a0[6] += wv.x * h1.z; a0[7] += wv.x * h1.w;
            a1[0] += wv.y * h0.x; a1[1] += wv.y * h0.y; a1[2] += wv.y * h0.z; a1[3] += wv.y * h0.w;
            a1[4] += wv.y * h1.x; a1[5] += wv.y * h1.y; a1[6] += wv.y * h1.z; a1[7] += wv.y * h1.w;
            a2[0] += wv.z * h0.x; a2[1] += wv.z * h0.y; a2[2] += wv.z * h0.z; a2[3] += wv.z * h0.w;
            a2[4] += wv.z * h1.x; a2[5] += wv.z * h1.y; a2[6] += wv.z * h1.z; a2[7] += wv.z * h1.w;
        }
        // reduce over 4 ksx within each wave (lane distance 16, 32)
#pragma unroll
        for (int i = 0; i < 8; ++i) {
            a0[i] += __shfl_xor(a0[i], 16); a0[i] += __shfl_xor(a0[i], 32);
            a1[i] += __shfl_xor(a1[i], 16); a1[i] += __shfl_xor(a1[i], 32);
            a2[i] += __shfl_xor(a2[i], 16); a2[i] += __shfl_xor(a2[i], 32);
        }
        __syncthreads();   // h_lds reads done; safe to reuse as 'red'
        if (lane < 16) {
            float* rp = red + (wid * 16 + lane) * 24;
#pragma unroll
            for (int i = 0; i < 8; ++i) { rp[i] = a0[i]; rp[8 + i] = a1[i]; rp[16 + i] = a2[i]; }
        }
        __syncthreads();
        if (tid < 128) {
            int fb = tid & 31;
            int rr_ = ((tid >> 5) << 2) | (fb >> 3);
            int bif = fb & 7;
            float hr = bh_r, hz = bh_z, hn = bh_n;
#pragma unroll
            for (int w2 = 0; w2 < 4; ++w2) {
                const float* rp = red + (w2 * 16 + rr_) * 24;
                hr += rp[bif];
                hz += rp[8 + bif];
                hn += rp[16 + bif];
            }
            int j = j0 + (tid >> 5);
            float r_ = 1.f / (1.f + __expf(-(xr + hr)));
            float z_ = 1.f / (1.f + __expf(-(xz + hz)));
            float pre = xn + r_ * hn;
            float e2 = __expf(-2.f * fabsf(pre));
            float tn = (1.f - e2) / (1.f + e2);
            float n_ = (pre >= 0.f) ? tn : -tn;
            float hnew = (1.f - z_) * n_ + z_ * hold;
            hold = hnew;
            // pack 4 consecutive b into one u64 of halves; lane fb%4==0 stores (r6-proven)
            float h1v = __shfl_xor(hnew, 1);
            float lo_f = (fb & 1) ? h1v : hnew;
            float hi_f = (fb & 1) ? hnew : h1v;
            __half2 v2 = __floats2half2_rn(lo_f, hi_f);
            union { __half2 h2; unsigned u; } cv;
            cv.h2 = v2;
            unsigned pa = cv.u;
            unsigned pb = (unsigned)__shfl_xor((int)pa, 2);
            u64 pku = ((fb & 2) == 0) ? ((u64)pa | ((u64)pb << 32))
                                      : ((u64)pb | ((u64)pa << 32));
            if ((fb & 3) == 0)
                __hip_atomic_store(&hnxt[j * 8 + (fb >> 2)], pku,
                                   __ATOMIC_RELAXED, __HIP_MEMORY_SCOPE_AGENT);
            fcred[tid] = hnew * fw;
            // drain this wave's h stores to L3 before the arrival add below
            __builtin_amdgcn_s_waitcnt(0);
        }
        xr = nxr; xz = nxz; xn = nxn;
        __syncthreads();
        if (tid < 32) {
            float s = fcred[tid] + fcred[32 + tid] + fcred[64 + tid] + fcred[96 + tid];
            __hip_atomic_store(&fcpart[(size_t)blk * 32000 + t * 32 + tid], s,
                               __ATOMIC_RELAXED, __HIP_MEMORY_SCOPE_AGENT);
        }

        // ---- monotone 8-line grid barrier (no fences, no reset) ----
        if (tid == 0) {
            unsigned target = 160u * (unsigned)(t + 1);
            __hip_atomic_fetch_add(&bar[(blk & 7) * 32], 1u,
                                   __ATOMIC_RELAXED, __HIP_MEMORY_SCOPE_AGENT);
            for (;;) {
                unsigned s = 0;
#pragma unroll
                for (int i = 0; i < 8; ++i)
                    s += __hip_atomic_load(&bar[i * 32], __ATOMIC_RELAXED,
                                           __HIP_MEMORY_SCOPE_AGENT);
                if (s >= target) break;
                __builtin_amdgcn_s_sleep(1);
            }
        }
        __syncthreads();
        __atomic_signal_fence(__ATOMIC_SEQ_CST);   // compiler-only ordering
    }
}

// ---------------------------------------------------------------------------
// K9: final fc reduction: out[b*1000+t] = fc_b + sum_blk fcpart[blk][t][b]
__global__ void k_fc(const float* __restrict__ fcpart, const float* __restrict__ fcb,
                     float* __restrict__ out) {
    int gid = blockIdx.x * 256 + threadIdx.x;  // < 32000
    int t = gid >> 5;
    int b = gid & 31;
    float s = fcb[0];
    for (int blk = 0; blk < 160; ++blk) s += fcpart[(size_t)blk * 32000 + t * 32 + b];
    out[(size_t)b * 1000 + t] = s;
}

// ---------------------------------------------------------------------------
extern "C" void kernel_launch(void* const* d_in, const int* in_sizes, int n_in,
                              void* d_out, int out_size, void* d_ws, size_t ws_size,
                              hipStream_t stream) {
    const float* x      = (const float*)d_in[0];
    const float* a_vals = (const float*)d_in[1];
    const float* w_vals = (const float*)d_in[2];
    const float* dcls_w = (const float*)d_in[3];
    const float* dcls_p = (const float*)d_in[4];
    const float* dcls_b = (const float*)d_in[5];
    const float* gamma  = (const float*)d_in[6];
    const float* beta   = (const float*)d_in[7];
    const float* W_ih   = (const float*)d_in[8];
    const float* W_hh   = (const float*)d_in[9];
    const float* b_ih   = (const float*)d_in[10];
    const float* b_hh   = (const float*)d_in[11];
    const float* fc_w   = (const float*)d_in[12];
    const float* fc_b   = (const float*)d_in[13];
    char* w = (char*)d_ws;

    // ws layout (bytes). Peak total: ~164.0 MB.
    //   [0, 122,880,000)           xpH   fp16 32000x1920  -- phase D
    //       overlay [0, 81,920,000)        ybcgt fp32     -- phases A-B (dead before GEMM)
    //   [122,880,000, 163,840,000) seqH  fp16 32000x640   -- phases B-C
    //       overlay: hp fp32 + dk fp32  -- phase A;  fcpart fp32 -- phase D
    //   [163,840,000, 163,921,920) hgu   u64 2x5120 (h dbuf, 4 packed fp16 per u64)
    //   [164,003,840, 164,004,352) bnsum fp32 128
    //   [164,004,352, 164,004,864) bnp   fp32 128
    //   [164,004,864, 164,005,888) bar   u32 8x32 (128B-spaced monotone counters)
    __half* xpH    = (__half*)(w);
    float* ybcgt   = (float*)(w);
    __half* seqH   = (__half*)(w + 122880000);
    float* hp      = (float*)(w + 122880000);
    float* dk      = (float*)(w + 122880000 + 4352000);
    float* fcpart  = (float*)(w + 122880000);
    u64* hgu       = (u64*)(w + 163840000);
    float* bnsum   = (float*)(w + 164003840);
    unsigned* bar  = (unsigned*)(w + 164004864);

    // zero h0 double-buffer + bn accumulators + bnp + barrier counters (tail spans all)
    hipMemsetAsync(w + 163840000, 0, 165888, stream);

    k_dk<<<dim3(315), dim3(256), 0, stream>>>(dcls_w, dcls_p, dk);
    k_ema<<<dim3(1088), dim3(256), 0, stream>>>(x, a_vals, w_vals, hp);
    k_conv<<<dim3(4, 10, 32), dim3(256), 0, stream>>>(hp, dk, dcls_b, ybcgt);
    k_bnstat<<<dim3(640), dim3(256), 0, stream>>>(ybcgt, bnsum);
    k_bnfin<<<dim3(1), dim3(64), 0, stream>>>(bnsum, gamma, beta, (float*)(w + 164004352));
    k_tr<<<dim3(16, 10, 32), dim3(256), 0, stream>>>(ybcgt, (float*)(w + 164004352), seqH);
    k_gemm<<<dim3(15, 250), dim3(256), 0, stream>>>(seqH, W_ih, b_ih, xpH);

    {
        const __half* xp_a = xpH;
        void* args[] = {(void*)&xp_a, (void*)&W_hh, (void*)&b_hh, (void*)&fc_w,
                        (void*)&hgu, (void*)&fcpart, (void*)&bar};
        hipLaunchCooperativeKernel((void*)k_gru, dim3(160), dim3(256), args, 0, stream);
    }

    k_fc<<<dim3(125), dim3(256), 0, stream>>>(fcpart, fc_b, (float*)d_out);
}

// Round 12
// 6934.103 us; speedup vs baseline: 1.3147x; 1.0420x over previous
//
#include <hip/hip_runtime.h>
#include <hip/hip_fp16.h>
#include <cstdint>

typedef float f4 __attribute__((ext_vector_type(4)));
typedef unsigned long long u64;

// Problem constants
// B=32, F=34, T=1000, K=7, S=3, F_DOWN=10, C=64, H=640, 3H=1920, T_MAX=9, PAD=4, MS_KS=200

// ---------------------------------------------------------------------------
// K1: build DCLS kernel dk[h][i][tau], h<640, i<14, tau<9
__global__ void k_dk(const float* __restrict__ dcls_w, const float* __restrict__ dcls_p,
                     float* __restrict__ dk) {
    int idx = blockIdx.x * 256 + threadIdx.x;
    if (idx >= 640 * 126) return;
    int h = idx / 126;
    int r = idx % 126;
    int i = r / 9;
    int tau = r % 9;
    float p = dcls_p[h * 14 + i];
    p = fminf(fmaxf(p, 0.f), 8.f);
    float tri = fmaxf(1.f - fabsf((float)tau - p), 0.f);
    dk[idx] = dcls_w[h * 14 + i] * tri;
}

// ---------------------------------------------------------------------------
// K2: EMA lowpass (200-tap truncated, exact) + highpass. hp[b][f][t]
__global__ void k_ema(const float* __restrict__ x, const float* __restrict__ a_vals,
                      const float* __restrict__ w_vals, float* __restrict__ hp) {
    __shared__ float xr[1024];
    int bf = blockIdx.x;               // b*34+f
    int f = bf % 34;
    int tid = threadIdx.x;
    const float* xs = x + (size_t)bf * 1000;
    for (int i = tid; i < 1000; i += 256) xr[i] = xs[i];
    for (int i = 1000 + tid; i < 1024; i += 256) xr[i] = 0.f;
    __syncthreads();
    float a = a_vals[f], wv = w_vals[f];
    float om = 1.f - a;
    int t1 = tid, t2 = tid + 256, t3 = tid + 512, t4 = tid + 768;
    bool v4 = (t4 < 1000);
    float a0 = 0.f, a1 = 0.f, a2 = 0.f, a3 = 0.f;
    float coef = a;
    for (int k = 0; k < 200; ++k) {
        a0 += (k <= t1 ? xr[t1 - k] : 0.f) * coef;
        a1 += xr[t2 - k] * coef;
        a2 += xr[t3 - k] * coef;
        a3 += (v4 ? xr[t4 - k] : 0.f) * coef;
        coef *= om;
    }
    float* op = hp + (size_t)bf * 1000;
    op[t1] = xr[t1] - wv * a0;
    op[t2] = xr[t2] - wv * a1;
    op[t3] = xr[t3] - wv * a2;
    if (v4) op[t4] = xr[t4] - wv * a3;
}

// ---------------------------------------------------------------------------
// K3: DCLS grouped conv. ybcgt[b][h=c*10+g][t] = bias[g*64+c] + sum_{i,tau} u * dk
__global__ void __launch_bounds__(256) k_conv(const float* __restrict__ hp,
                                              const float* __restrict__ dk,
                                              const float* __restrict__ dcls_b,
                                              float* __restrict__ ybcgt) {
    __shared__ float u[2 * 7 * 264];    // [pm][kk][264]
    __shared__ float dks[64 * 126];
    int tid = threadIdx.x;
    int t0 = blockIdx.x * 256;
    int g = blockIdx.y;
    int b = blockIdx.z;
    for (int idx = tid; idx < 8064; idx += 256) dks[idx] = dk[g * 8064 + idx];
    for (int idx = tid; idx < 3696; idx += 256) {
        int pm = idx / 1848;
        int rem = idx % 1848;
        int kk = rem / 264;
        int tt = rem % 264;
        int tg = t0 - 4 + tt;
        float v = (tg >= 0 && tg < 1000) ? hp[((size_t)(b * 34 + g * 3 + kk)) * 1000 + tg] : 0.f;
        u[idx] = pm ? fmaxf(-v, 0.f) : fmaxf(v, 0.f);
    }
    __syncthreads();
    int tl = tid & 63;
    int cg4 = tid >> 6;     // 0..3, c = cg4*16+ci
    float acc[16][4];
#pragma unroll
    for (int ci = 0; ci < 16; ++ci)
#pragma unroll
        for (int tq = 0; tq < 4; ++tq) acc[ci][tq] = 0.f;

    for (int i = 0; i < 14; ++i) {
#pragma unroll
        for (int tau = 0; tau < 9; ++tau) {
            const float* ub = u + i * 264 + tl + tau;
            float u0 = ub[0];
            float u1 = ub[64];
            float u2 = ub[128];
            float u3 = ub[192];
            const float* dp = dks + cg4 * 16 * 126 + i * 9 + tau;
#pragma unroll
            for (int ci = 0; ci < 16; ++ci) {
                float dv = dp[ci * 126];
                acc[ci][0] += u0 * dv;
                acc[ci][1] += u1 * dv;
                acc[ci][2] += u2 * dv;
                acc[ci][3] += u3 * dv;
            }
        }
    }
#pragma unroll
    for (int ci = 0; ci < 16; ++ci) {
        int c = cg4 * 16 + ci;
        float bias = dcls_b[g * 64 + c];
        size_t base = ((size_t)(b * 640 + c * 10 + g)) * 1000;
#pragma unroll
        for (int tq = 0; tq < 4; ++tq) {
            int t = t0 + tq * 64 + tl;
            if (t < 1000) ybcgt[base + t] = acc[ci][tq] + bias;
        }
    }
}

// ---------------------------------------------------------------------------
// K4: BN stats: per channel c sum & sumsq over (b,g,t). bnsum[0..63]=sum, [64..127]=sumsq
__global__ void k_bnstat(const float* __restrict__ ybcgt, float* __restrict__ bnsum) {
    int c = blockIdx.x / 10;
    int g = blockIdx.x % 10;
    int tid = threadIdx.x;
    float s = 0.f, q = 0.f;
    const float* base = ybcgt + ((size_t)(c * 10 + g)) * 1000;
    for (int b = 0; b < 32; ++b) {
        const float* p = base + (size_t)b * 640000;
        for (int t = tid; t < 1000; t += 256) {
            float v = p[t];
            s += v;
            q += v * v;
        }
    }
    for (int off = 1; off < 64; off <<= 1) {
        s += __shfl_xor(s, off);
        q += __shfl_xor(q, off);
    }
    __shared__ float rs[4], rq[4];
    if ((tid & 63) == 0) { rs[tid >> 6] = s; rq[tid >> 6] = q; }
    __syncthreads();
    if (tid == 0) {
        s = rs[0] + rs[1] + rs[2] + rs[3];
        q = rq[0] + rq[1] + rq[2] + rq[3];
        atomicAdd(&bnsum[c], s);
        atomicAdd(&bnsum[64 + c], q);
    }
}

// K5: BN finalize -> bnp[c]=scale, bnp[64+c]=shift
__global__ void k_bnfin(const float* __restrict__ bnsum, const float* __restrict__ gamma,
                        const float* __restrict__ beta, float* __restrict__ bnp) {
    int c = threadIdx.x;
    const float inv_n = 1.f / 320000.f;
    float mean = bnsum[c] * inv_n;
    float var = bnsum[64 + c] * inv_n - mean * mean;
    float sc = gamma[c] * rsqrtf(var + 1e-5f);
    bnp[c] = sc;
    bnp[64 + c] = beta[c] - mean * sc;
}

// ---------------------------------------------------------------------------
// K6: fused transpose + BN + sigmoid: seq[(t*32+b)*640 + h] = sigmoid(scale*y + shift) (fp16)
__global__ void k_tr(const float* __restrict__ ybcgt, const float* __restrict__ bnp,
                     __half* __restrict__ seq) {
    __shared__ float tile[64 * 65];
    int tid = threadIdx.x;
    int tt0 = blockIdx.x * 64;
    int h0 = blockIdx.y * 64;
    int b = blockIdx.z;
    int tx = tid & 63;
    int ty = tid >> 6;
#pragma unroll
    for (int r = 0; r < 16; ++r) {
        int hh = r * 4 + ty;
        int t = tt0 + tx;
        float v = (t < 1000) ? ybcgt[((size_t)(b * 640 + h0 + hh)) * 1000 + t] : 0.f;
        int c = (h0 + hh) / 10;
        float sarg = bnp[c] * v + bnp[64 + c];
        tile[hh * 65 + tx] = 1.f / (1.f + __expf(-sarg));
    }
    __syncthreads();
#pragma unroll
    for (int r = 0; r < 16; ++r) {
        int t = tt0 + r * 4 + ty;
        if (t < 1000)
            seq[((size_t)t * 32 + b) * 640 + h0 + tx] = __float2half(tile[tx * 65 + r * 4 + ty]);
    }
}

// ---------------------------------------------------------------------------
// K7: x_proj GEMM (r7/r10 version, passing): BM=BN=128, BK=8, 256 thr, 8x8 micro,
// 16 NAMED f4 accs; __launch_bounds__(256,4); Bs swizzled to break bank alias.
#define BCOL(c) ((c) + (((c) >> 5) << 2))
__global__ void __launch_bounds__(256, 4) k_gemm(const __half* __restrict__ A,
                                                 const float* __restrict__ W,
                                                 const float* __restrict__ bih,
                                                 __half* __restrict__ C) {
    __shared__ float As[8][128];
    __shared__ float Bs[8][140];
    int tid = threadIdx.x;
    int n0 = blockIdx.x * 128;
    int m0 = blockIdx.y * 128;
    int tx = tid & 15;          // n-subtile: cols n0 + tx*8 .. +7
    int ty = tid >> 4;          // m-subtile: rows m0 + ty*8 .. +7
    int lm = tid >> 1;
    int lk4 = (tid & 1) * 4;
    int lmB = BCOL(lm);
    const int bc0 = BCOL(tx * 8);
    const int bc1 = BCOL(tx * 8 + 4);
    const __half* Ab = A + (size_t)(m0 + lm) * 640 + lk4;
    const float* Bb = W + (size_t)(n0 + lm) * 640 + lk4;

    f4 c0a = {0,0,0,0}, c0b = {0,0,0,0}, c1a = {0,0,0,0}, c1b = {0,0,0,0};
    f4 c2a = {0,0,0,0}, c2b = {0,0,0,0}, c3a = {0,0,0,0}, c3b = {0,0,0,0};
    f4 c4a = {0,0,0,0}, c4b = {0,0,0,0}, c5a = {0,0,0,0}, c5b = {0,0,0,0};
    f4 c6a = {0,0,0,0}, c6b = {0,0,0,0}, c7a = {0,0,0,0}, c7b = {0,0,0,0};

    for (int kt = 0; kt < 80; ++kt) {
        float2 araw = *(const float2*)(Ab + (size_t)kt * 8);   // 4 halves
        const __half2* ah = (const __half2*)&araw;
        float2 a01 = __half22float2(ah[0]);
        float2 a23 = __half22float2(ah[1]);
        float4 bv = *(const float4*)(Bb + (size_t)kt * 8);
        __syncthreads();
        As[lk4 + 0][lm] = a01.x; As[lk4 + 1][lm] = a01.y;
        As[lk4 + 2][lm] = a23.x; As[lk4 + 3][lm] = a23.y;
        Bs[lk4 + 0][lmB] = bv.x; Bs[lk4 + 1][lmB] = bv.y;
        Bs[lk4 + 2][lmB] = bv.z; Bs[lk4 + 3][lmB] = bv.w;
        __syncthreads();
#pragma unroll
        for (int kk = 0; kk < 8; ++kk) {
            f4 blo = *(const f4*)&Bs[kk][bc0];
            f4 bhi = *(const f4*)&Bs[kk][bc1];
            f4 alo = *(const f4*)&As[kk][ty * 8];
            f4 ahi = *(const f4*)&As[kk][ty * 8 + 4];
            c0a += alo.x * blo; c0b += alo.x * bhi;
            c1a += alo.y * blo; c1b += alo.y * bhi;
            c2a += alo.z * blo; c2b += alo.z * bhi;
            c3a += alo.w * blo; c3b += alo.w * bhi;
            c4a += ahi.x * blo; c4b += ahi.x * bhi;
            c5a += ahi.y * blo; c5b += ahi.y * bhi;
            c6a += ahi.z * blo; c6b += ahi.z * bhi;
            c7a += ahi.w * blo; c7b += ahi.w * bhi;
        }
    }
    f4 bblo = *(const f4*)&bih[n0 + tx * 8];
    f4 bbhi = *(const f4*)&bih[n0 + tx * 8 + 4];
    union { __half h[8]; float4 v; } ob;
#define STORE_ROW(i, ra, rb)                                                     \
    {                                                                            \
        f4 lo = ra + bblo; f4 hi = rb + bbhi;                                    \
        ob.h[0] = __float2half(lo.x); ob.h[1] = __float2half(lo.y);              \
        ob.h[2] = __float2half(lo.z); ob.h[3] = __float2half(lo.w);              \
        ob.h[4] = __float2half(hi.x); ob.h[5] = __float2half(hi.y);              \
        ob.h[6] = __float2half(hi.z); ob.h[7] = __float2half(hi.w);              \
        *(float4*)&C[(size_t)(m0 + ty * 8 + i) * 1920 + n0 + tx * 8] = ob.v;     \
    }
    STORE_ROW(0, c0a, c0b) STORE_ROW(1, c1a, c1b) STORE_ROW(2, c2a, c2b)
    STORE_ROW(3, c3a, c3b) STORE_ROW(4, c4a, c4b) STORE_ROW(5, c5a, c5b)
    STORE_ROW(6, c6a, c6b) STORE_ROW(7, c7a, c7b)
#undef STORE_ROW
}

// ---------------------------------------------------------------------------
// K8: persistent GRU = round-11 with ONE change: 512 threads/block (2 waves/SIMD
// instead of 1 -> ds_read/FMA latency overlap; halves per-thread matvec+staging).
// ksplit 32 (ksx=tid>>4), matvec 20 iters, staging 10 u64 loads/thread,
// red overlay [8][16][24]. Everything else identical: fp16 h exchange,
// stride-32 h_lds, 8-line monotone fetch_add barrier, same gate/epilogue.
__global__ void __launch_bounds__(512, 1) k_gru(const __half* __restrict__ xp,
                                                const float* __restrict__ Whh,
                                                const float* __restrict__ bhh,
                                                const float* __restrict__ fcw,
                                                u64* __restrict__ hgu,
                                                float* __restrict__ fcpart,
                                                unsigned* __restrict__ bar) {
    __shared__ __align__(16) float w_lds[640 * 16];   // [k][jj*4+g], g<3  (40960 B)
    __shared__ __align__(16) float h_lds[640 * 32];   // full h staging    (81920 B)
    float* red = h_lds;            // overlay after compute: [8][16][24] = 3072 floats
    float* fcred = h_lds + 3072;   // 128 floats

    const int tid = threadIdx.x;
    const int blk = blockIdx.x;
    const int j0 = blk * 4;
    const int ksx = tid >> 4;            // 0..31
    const int jj = (tid >> 2) & 3;
    const int bg = tid & 3;
    const int lane = tid & 63;
    const int wid = tid >> 6;            // 0..7

    // Load the block's 12 W_hh rows into LDS once (persists across all steps)
    for (int r = 0; r < 12; ++r) {
        int wjj = r / 3, wg = r % 3;
        const float* src = Whh + (size_t)(wg * 640 + j0 + wjj) * 640;
        for (int k = tid; k < 640; k += 512) w_lds[k * 16 + wjj * 4 + wg] = src[k];
    }
    float bh_r = 0.f, bh_z = 0.f, bh_n = 0.f, fw = 0.f, hold = 0.f;
    if (tid < 128) {
        int fj = j0 + (tid >> 5);
        bh_r = bhh[fj];
        bh_z = bhh[640 + fj];
        bh_n = bhh[1280 + fj];
        fw = fcw[fj];
    }
    __syncthreads();

    // preload xp for t=0 (plain cached loads)
    float xr = 0.f, xz = 0.f, xn = 0.f;
    if (tid < 128) {
        const __half* xpt = xp + (size_t)(tid & 31) * 1920;
        int j = j0 + (tid >> 5);
        xr = __half2float(xpt[j]);
        xz = __half2float(xpt[640 + j]);
        xn = __half2float(xpt[1280 + j]);
    }

    for (int t = 0; t < 1000; ++t) {
        const u64* hcur = hgu + (size_t)(t & 1) * 5120;
        u64* hnxt = hgu + (size_t)((t + 1) & 1) * 5120;

        // batched h staging: 10 independent L3 atomic u64 loads (4 fp16 each)
        u64 rr[10];
#pragma unroll
        for (int i = 0; i < 10; ++i)
            rr[i] = __hip_atomic_load(&hcur[i * 512 + tid],
                                      __ATOMIC_RELAXED, __HIP_MEMORY_SCOPE_AGENT);
#pragma unroll
        for (int i = 0; i < 10; ++i) {
            int e = i * 512 + tid;             // e = k*8 + b/4
            union { u64 u; __half2 h2[2]; } pk;
            pk.u = rr[i];
            float2 lo = __half22float2(pk.h2[0]);
            float2 hi = __half22float2(pk.h2[1]);
            f4 v = {lo.x, lo.y, hi.x, hi.y};
            *(f4*)&h_lds[(e >> 3) * 32 + (e & 7) * 4] = v;   // 16B-aligned (stride 32)
        }
        __syncthreads();

        // prefetch xp for step t+1 (overlaps with compute below)
        float nxr = 0.f, nxz = 0.f, nxn = 0.f;
        if (t + 1 < 1000 && tid < 128) {
            const __half* xpt = xp + (size_t)(t + 1) * 61440 + (size_t)(tid & 31) * 1920;
            int j = j0 + (tid >> 5);
            nxr = __half2float(xpt[j]);
            nxz = __half2float(xpt[640 + j]);
            nxn = __half2float(xpt[1280 + j]);
        }

        float a0[8], a1[8], a2[8];
#pragma unroll
        for (int i = 0; i < 8; ++i) { a0[i] = 0.f; a1[i] = 0.f; a2[i] = 0.f; }

#pragma unroll 4
        for (int ii = 0; ii < 20; ++ii) {
            int k = ii * 32 + ksx;
            float4 wv = *(const float4*)(w_lds + k * 16 + jj * 4);
            float4 h0 = *(const float4*)(h_lds + k * 32 + bg * 8);
            float4 h1 = *(const float4*)(h_lds + k * 32 + bg * 8 + 4);
            a0[0] += wv.x * h0.x; a0[1] += wv.x * h0.y; a0[2] += wv.x * h0.z; a0[3] += wv.x * h0.w;
            a0[4] += wv.x * h1.x; a0[5] += wv.x * h1.y; a0[6] += wv.x * h1.z; a0[7] += wv.x * h1.w;
            a1[0] += wv.y * h0.x; a1[1] += wv.y * h0.y; a1[2] += wv.y * h0.z; a1[3] += wv.y * h0.w;
            a1[4] += wv.y * h1.x; a1[5] += wv.y * h1.y; a1[6] += wv.y * h1.z; a1[7] += wv.y * h1.w;
            a2[0] += wv.z * h0.x; a2[1] += wv.z * h0.y; a2[2] += wv.z * h0.z; a2[3] += wv.z * h0.w;
            a2[4] += wv.z * h1.x; a2[5] += wv.z * h1.y; a2[6] += wv.z * h1.z; a2[7] += wv.z * h1.w;
        }
        // reduce over the wave's 4 ksx values (lane distance 16, 32)
#pragma unroll
        for (int i = 0; i < 8; ++i) {
            a0[i] += __shfl_xor(a0[i], 16); a0[i] += __shfl_xor(a0[i], 32);
            a1[i] += __shfl_xor(a1[i], 16); a1[i] += __shfl_xor(a1[i], 32);
            a2[i] += __shfl_xor(a2[i], 16); a2[i] += __shfl_xor(a2[i], 32);
        }
        __syncthreads();   // h_lds reads done; safe to reuse as 'red'
        if (lane < 16) {
            float* rp = red + (wid * 16 + lane) * 24;
#pragma unroll
            for (int i = 0; i < 8; ++i) { rp[i] = a0[i]; rp[8 + i] = a1[i]; rp[16 + i] = a2[i]; }
        }
        __syncthreads();
        if (tid < 128) {
            int fb = tid & 31;
            int rr_ = ((tid >> 5) << 2) | (fb >> 3);
            int bif = fb & 7;
            float hr = bh_r, hz = bh_z, hn = bh_n;
#pragma unroll
            for (int w2 = 0; w2 < 8; ++w2) {
                const float* rp = red + (w2 * 16 + rr_) * 24;
                hr += rp[bif];
                hz += rp[8 + bif];
                hn += rp[16 + bif];
            }
            int j = j0 + (tid >> 5);
            float r_ = 1.f / (1.f + __expf(-(xr + hr)));
            float z_ = 1.f / (1.f + __expf(-(xz + hz)));
            float pre = xn + r_ * hn;
            float e2 = __expf(-2.f * fabsf(pre));
            float tn = (1.f - e2) / (1.f + e2);
            float n_ = (pre >= 0.f) ? tn : -tn;
            float hnew = (1.f - z_) * n_ + z_ * hold;
            hold = hnew;
            // pack 4 consecutive b into one u64 of halves; lane fb%4==0 stores
            float h1v = __shfl_xor(hnew, 1);
            float lo_f = (fb & 1) ? h1v : hnew;
            float hi_f = (fb & 1) ? hnew : h1v;
            __half2 v2 = __floats2half2_rn(lo_f, hi_f);
            union { __half2 h2; unsigned u; } cv;
            cv.h2 = v2;
            unsigned pa = cv.u;
            unsigned pb = (unsigned)__shfl_xor((int)pa, 2);
            u64 pku = ((fb & 2) == 0) ? ((u64)pa | ((u64)pb << 32))
                                      : ((u64)pb | ((u64)pa << 32));
            if ((fb & 3) == 0)
                __hip_atomic_store(&hnxt[j * 8 + (fb >> 2)], pku,
                                   __ATOMIC_RELAXED, __HIP_MEMORY_SCOPE_AGENT);
            fcred[tid] = hnew * fw;
            // drain this wave's h stores to L3 before the arrival add below
            __builtin_amdgcn_s_waitcnt(0);
        }
        xr = nxr; xz = nxz; xn = nxn;
        __syncthreads();
        if (tid < 32) {
            float s = fcred[tid] + fcred[32 + tid] + fcred[64 + tid] + fcred[96 + tid];
            __hip_atomic_store(&fcpart[(size_t)blk * 32000 + t * 32 + tid], s,
                               __ATOMIC_RELAXED, __HIP_MEMORY_SCOPE_AGENT);
        }

        // ---- monotone 8-line grid barrier (no fences, no reset) ----
        if (tid == 0) {
            unsigned target = 160u * (unsigned)(t + 1);
            __hip_atomic_fetch_add(&bar[(blk & 7) * 32], 1u,
                                   __ATOMIC_RELAXED, __HIP_MEMORY_SCOPE_AGENT);
            for (;;) {
                unsigned s = 0;
#pragma unroll
                for (int i = 0; i < 8; ++i)
                    s += __hip_atomic_load(&bar[i * 32], __ATOMIC_RELAXED,
                                           __HIP_MEMORY_SCOPE_AGENT);
                if (s >= target) break;
                __builtin_amdgcn_s_sleep(1);
            }
        }
        __syncthreads();
        __atomic_signal_fence(__ATOMIC_SEQ_CST);   // compiler-only ordering
    }
}

// ---------------------------------------------------------------------------
// K9: final fc reduction: out[b*1000+t] = fc_b + sum_blk fcpart[blk][t][b]
__global__ void k_fc(const float* __restrict__ fcpart, const float* __restrict__ fcb,
                     float* __restrict__ out) {
    int gid = blockIdx.x * 256 + threadIdx.x;  // < 32000
    int t = gid >> 5;
    int b = gid & 31;
    float s = fcb[0];
    for (int blk = 0; blk < 160; ++blk) s += fcpart[(size_t)blk * 32000 + t * 32 + b];
    out[(size_t)b * 1000 + t] = s;
}

// ---------------------------------------------------------------------------
extern "C" void kernel_launch(void* const* d_in, const int* in_sizes, int n_in,
                              void* d_out, int out_size, void* d_ws, size_t ws_size,
                              hipStream_t stream) {
    const float* x      = (const float*)d_in[0];
    const float* a_vals = (const float*)d_in[1];
    const float* w_vals = (const float*)d_in[2];
    const float* dcls_w = (const float*)d_in[3];
    const float* dcls_p = (const float*)d_in[4];
    const float* dcls_b = (const float*)d_in[5];
    const float* gamma  = (const float*)d_in[6];
    const float* beta   = (const float*)d_in[7];
    const float* W_ih   = (const float*)d_in[8];
    const float* W_hh   = (const float*)d_in[9];
    const float* b_ih   = (const float*)d_in[10];
    const float* b_hh   = (const float*)d_in[11];
    const float* fc_w   = (const float*)d_in[12];
    const float* fc_b   = (const float*)d_in[13];
    char* w = (char*)d_ws;

    // ws layout (bytes). Peak total: ~164.0 MB.
    //   [0, 122,880,000)           xpH   fp16 32000x1920  -- phase D
    //       overlay [0, 81,920,000)        ybcgt fp32     -- phases A-B (dead before GEMM)
    //   [122,880,000, 163,840,000) seqH  fp16 32000x640   -- phases B-C
    //       overlay: hp fp32 + dk fp32  -- phase A;  fcpart fp32 -- phase D
    //   [163,840,000, 163,921,920) hgu   u64 2x5120 (h dbuf, 4 packed fp16 per u64)
    //   [164,003,840, 164,004,352) bnsum fp32 128
    //   [164,004,352, 164,004,864) bnp   fp32 128
    //   [164,004,864, 164,005,888) bar   u32 8x32 (128B-spaced monotone counters)
    __half* xpH    = (__half*)(w);
    float* ybcgt   = (float*)(w);
    __half* seqH   = (__half*)(w + 122880000);
    float* hp      = (float*)(w + 122880000);
    float* dk      = (float*)(w + 122880000 + 4352000);
    float* fcpart  = (float*)(w + 122880000);
    u64* hgu       = (u64*)(w + 163840000);
    float* bnsum   = (float*)(w + 164003840);
    unsigned* bar  = (unsigned*)(w + 164004864);

    // zero h0 double-buffer + bn accumulators + bnp + barrier counters (tail spans all)
    hipMemsetAsync(w + 163840000, 0, 165888, stream);

    k_dk<<<dim3(315), dim3(256), 0, stream>>>(dcls_w, dcls_p, dk);
    k_ema<<<dim3(1088), dim3(256), 0, stream>>>(x, a_vals, w_vals, hp);
    k_conv<<<dim3(4, 10, 32), dim3(256), 0, stream>>>(hp, dk, dcls_b, ybcgt);
    k_bnstat<<<dim3(640), dim3(256), 0, stream>>>(ybcgt, bnsum);
    k_bnfin<<<dim3(1), dim3(64), 0, stream>>>(bnsum, gamma, beta, (float*)(w + 164004352));
    k_tr<<<dim3(16, 10, 32), dim3(256), 0, stream>>>(ybcgt, (float*)(w + 164004352), seqH);
    k_gemm<<<dim3(15, 250), dim3(256), 0, stream>>>(seqH, W_ih, b_ih, xpH);

    {
        const __half* xp_a = xpH;
        void* args[] = {(void*)&xp_a, (void*)&W_hh, (void*)&b_hh, (void*)&fc_w,
                        (void*)&hgu, (void*)&fcpart, (void*)&bar};
        hipLaunchCooperativeKernel((void*)k_gru, dim3(160), dim3(512), args, 0, stream);
    }

    k_fc<<<dim3(125), dim3(256), 0, stream>>>(fcpart, fc_b, (float*)d_out);
}